// Round 23
// baseline (425.132 us; speedup 1.0000x reference)
//
#include <hip/hip_runtime.h>
#include <hip/hip_bf16.h>
#include <math.h>

#define HH 384
#define WW 384
#define NPIX (HH*WW)        // 147456
#define BB 2
#define CC 16
#define NKF 9437184         // pred_kspace float count

__device__ inline float2 cmul(float2 a, float2 b) {
    return make_float2(a.x*b.x - a.y*b.y, a.x*b.y + a.y*b.x);
}
__device__ inline float bf2f(unsigned short u) {
    union { unsigned int i; float f; } c; c.i = ((unsigned)u) << 16; return c.f;
}
__device__ inline float2 loadc2(const void* p, int dt, size_t i) {
    if (dt == 1) { ushort2 u = ((const ushort2*)p)[i];
        return make_float2(bf2f(u.x), bf2f(u.y)); }
    if (dt == 2) { double2 d = ((const double2*)p)[i];
        return make_float2((float)d.x, (float)d.y); }
    return ((const float2*)p)[i];
}
__device__ inline float loads1(const void* p, int dt, size_t i) {
    if (dt == 1) return bf2f(((const unsigned short*)p)[i]);
    if (dt == 2) return (float)((const double*)p)[i];
    return ((const float*)p)[i];
}
__device__ inline int flex_int1(const void* p) {
    unsigned v = ((const unsigned*)p)[0];
    if (v < 1000000u) return (int)v;
    float f = ((const float*)p)[0];
    if (f > -1e6f && f < 1e6f && f == floorf(f)) return (int)f;
    return (int)((const double*)p)[0];
}
__device__ inline int flex_int_arr(const void* p, int i) {
    const unsigned* u = (const unsigned*)p;
    if (u[1] == 0u && u[3] == 0u) return (int)u[2*i];   // int64
    if (u[0] >= 1u && u[0] < 1000000u) return (int)u[i];// int32
    float f = ((const float*)p)[i];
    if (f > -1e6f && f < 1e6f) return (int)f;
    return (int)((const double*)p)[i];
}

__global__ void detect_dtype(const unsigned* __restrict__ q, int* dt)
{
    __shared__ int bad, sig;
    if (threadIdx.x == 0) { bad = 0; sig = 0; }
    __syncthreads();
    const unsigned short* q16 = (const unsigned short*)q;
    int mybad = 0, mysig = 0;
    for (int i = threadIdx.x; i < 8192; i += 256) {
        unsigned short u = q16[i];
        int e = (u >> 7) & 0xFF;
        if (!(e == 0 || (e >= 100 && e <= 140))) mybad++;
    }
    for (int i = threadIdx.x; i < 2048; i += 256) {
        unsigned hi = q[2*i + 1];
        int e = (hi >> 20) & 0x7FF;
        if (e >= 1003 && e <= 1040) mysig++;
    }
    atomicAdd(&bad, mybad);
    atomicAdd(&sig, mysig);
    __syncthreads();
    if (threadIdx.x == 0)
        *dt = (bad < 400) ? 1 : ((sig > 1950) ? 2 : 0);
}

// ---------------------------------------------------------------------------
// FFT-384; fftshift folded; ortho. MODE: 0 plain, 1 load-fused expand,
// 2 store-fused dc. NL = lines per block (8 rows / 16 cols for coalescing).
// ---------------------------------------------------------------------------
#define SP 385

template<int DIR, int AXIS, int MODE, int NL>
__global__ __launch_bounds__(256)
void fft384(const void* in, float2* out, const int* DTp, int srcExt,
            const void* aux1, const void* aux2,
            const int* FLAGp, const void* dcwp, float2* outk)
{
    __shared__ float2 tw[384];
    __shared__ float2 stage[NL * SP];
    __shared__ float2 work[4][384];
    const int tid = threadIdx.x;
    const int dt = (srcExt || MODE) ? *DTp : 0;
    for (int j = tid; j < 384; j += 256) {
        float s, c;
        sincosf(-6.283185307179586f * (float)j / 384.0f, &s, &c);
        tw[j] = make_float2(c, s);
    }
    const int BPI = 384 / NL;
    const int img = blockIdx.x / BPI;
    const int t0  = (blockIdx.x % BPI) * NL;
    const size_t base = (size_t)img * NPIX;
    float2* dst = out + base;

    if (AXIS == 0) {
        if (MODE == 1) {
            const float2* rim = (const float2*)aux1;
            const size_t rbase = (size_t)(img >> 4) * NPIX;
            for (int f = tid; f < NL*384; f += 256) {
                int l = f / 384, n = f - l*384;
                size_t pix = (size_t)(t0 + l)*384 + n;
                stage[l*SP + n] = cmul(rim[rbase + pix], loadc2(aux2, dt, base + pix));
            }
        } else {
            for (int f = tid; f < NL*384; f += 256) {
                int l = f / 384, n = f - l*384;
                stage[l*SP + n] = loadc2(in, dt, base + (size_t)(t0 + l)*384 + n);
            }
        }
    } else {
        for (int f = tid; f < NL*384; f += 256) {
            int l = f & (NL-1), n = f / NL;
            stage[l*SP + n] = loadc2(in, dt, base + (size_t)n*384 + (t0 + l));
        }
    }
    __syncthreads();
    const int g    = tid >> 6;
    const int lane = tid & 63;
    float2* w = work[g];
    const float SCALE = 0.05103103630798288f;
    for (int it = 0; it < NL/4; ++it) {
        const int l = it*4 + g;
        #pragma unroll
        for (int m = 0; m < 6; ++m) {
            int n = lane + 64*m;
            float2 v = stage[l*SP + n];
            float sgn = (n & 1) ? -1.f : 1.f;
            int q = n / 3;
            int r3 = n - 3*q;
            w[r3*128 + q] = make_float2(v.x*sgn, v.y*sgn);
        }
        __syncthreads();
        #pragma unroll
        for (int s = 0; s < 7; ++s) {
            const int h = 64 >> s;
            const int tstep = 3 << s;
            const int j = lane & (h-1);
            const int i = ((lane & ~(h-1)) << 1) | j;
            float2 t = tw[j * tstep];
            if (DIR < 0) t.y = -t.y;
            #pragma unroll
            for (int n1 = 0; n1 < 3; ++n1) {
                float2* a = w + (n1 << 7);
                float2 u = a[i], v = a[i+h];
                float2 d = make_float2(u.x - v.x, u.y - v.y);
                a[i]   = make_float2(u.x + v.x, u.y + v.y);
                a[i+h] = cmul(d, t);
            }
            __syncthreads();
        }
        #pragma unroll
        for (int half = 0; half < 2; ++half) {
            int k2 = lane + 64*half;
            int r  = __brev((unsigned)k2) >> 25;
            float2 a0 = w[r], a1 = w[128 + r], a2 = w[256 + r];
            float2 t1 = tw[k2];
            float2 t2 = tw[(2*k2) % 384];
            float2 w3 = tw[128], w3b = tw[256];
            if (DIR < 0) { t1.y=-t1.y; t2.y=-t2.y; w3.y=-w3.y; w3b.y=-w3b.y; }
            float2 b1 = cmul(a1, t1), b2 = cmul(a2, t2);
            float2 X0 = make_float2(a0.x + b1.x + b2.x, a0.y + b1.y + b2.y);
            float2 c1 = cmul(w3, b1), c2 = cmul(w3b, b2);
            float2 X1 = make_float2(a0.x + c1.x + c2.x, a0.y + c1.y + c2.y);
            float2 d1 = cmul(w3b, b1), d2 = cmul(w3, b2);
            float2 X2 = make_float2(a0.x + d1.x + d2.x, a0.y + d1.y + d2.y);
            float sc = (k2 & 1) ? -SCALE : SCALE;
            stage[l*SP + k2      ] = make_float2(X0.x*sc, X0.y*sc);
            stage[l*SP + k2 + 128] = make_float2(X1.x*sc, X1.y*sc);
            stage[l*SP + k2 + 256] = make_float2(X2.x*sc, X2.y*sc);
        }
        __syncthreads();
    }
    if (AXIS == 0) {
        for (int f = tid; f < NL*384; f += 256) {
            int l = f / 384, n = f - l*384;
            dst[(size_t)(t0 + l)*384 + n] = stage[l*SP + n];
        }
    } else {
        if (MODE == 2) {
            const int fl = *FLAGp;
            const float dw = loads1(dcwp, dt, 0);
            const int bb = img >> 4;
            for (int f = tid; f < NL*384; f += 256) {
                int l = f & (NL-1), n = f / NL;
                int wcol = t0 + l;
                size_t pix = (size_t)n*384 + wcol;
                float2 v = stage[l*SP + n];
                int m;
                switch (fl) {
                    case 0:  m = ((const unsigned char*)aux2)[bb*384 + wcol] != 0; break;
                    case 4:  m = ((const unsigned short*)aux2)[bb*384 + wcol] != 0; break;
                    case 3:  m = ((const unsigned long long*)aux2)[bb*384 + wcol] != 0ULL; break;
                    default: m = ((const unsigned int*)aux2)[bb*384 + wcol] != 0u; break;
                }
                if (m) {
                    float2 r = loadc2(aux1, dt, base + pix);
                    v.x -= (v.x - r.x)*dw;
                    v.y -= (v.y - r.y)*dw;
                }
                dst[pix] = v;
                outk[base + pix] = v;
            }
        } else {
            for (int f = tid; f < NL*384; f += 256) {
                int l = f & (NL-1), n = f / NL;
                dst[(size_t)n*384 + (t0 + l)] = stage[l*SP + n];
            }
        }
    }
}

__global__ void detect_mask(const unsigned char* __restrict__ m, int* flag)
{
    __shared__ int sA, sB, sC, sD, sE;
    if (threadIdx.x == 0) { sA = sB = sC = sD = sE = 0; }
    __syncthreads();
    for (int i = threadIdx.x; i < 768; i += 256) {
        unsigned char v = m[i];
        if (v > 1) atomicOr(&sA, 1);
        if ((i & 3) && v) atomicOr(&sB, 1);
    }
    const unsigned short* m16 = (const unsigned short*)m;
    for (int i = threadIdx.x; i < 384; i += 256)
        if (!(i & 1) && m16[i]) atomicOr(&sC, 1);
    const unsigned int* m32 = (const unsigned int*)m;
    for (int i = threadIdx.x; i < 192; i += 256) {
        if ((i & 1) && m32[i]) atomicOr(&sD, 1);
        if (!(i & 1) && m32[i]) atomicOr(&sE, 1);
    }
    __syncthreads();
    if (threadIdx.x == 0) {
        int f;
        if (!sA) { if (sB) f = 0; else if (sD) f = 2; else f = 3; }
        else     { if (sC) f = 4; else if (sE) f = 2; else f = 3; }
        *flag = f;
    }
}

template<bool WITH_STATS>
__global__ __launch_bounds__(256)
void reduce_sens(const float2* __restrict__ xin, const void* __restrict__ sens,
                 float2* __restrict__ ximg, const int* DTp,
                 float* __restrict__ partials)
{
    const int dt = *DTp;
    const int b = blockIdx.y;
    const int p = blockIdx.x*256 + threadIdx.x;
    float2 acc = make_float2(0.f, 0.f);
    for (int c = 0; c < CC; ++c) {
        size_t o = ((size_t)(b*CC + c))*NPIX + p;
        float2 a = xin[o];
        float2 s = loadc2(sens, dt, o);
        acc.x += a.x*s.x + a.y*s.y;
        acc.y += a.y*s.x - a.x*s.y;
    }
    ximg[(size_t)b*NPIX + p] = acc;
    if (WITH_STATS) {
        float sx = acc.x, sy = acc.y, qx = acc.x*acc.x, qy = acc.y*acc.y;
        #pragma unroll
        for (int o = 32; o > 0; o >>= 1) {
            sx += __shfl_down(sx, o, 64); sy += __shfl_down(sy, o, 64);
            qx += __shfl_down(qx, o, 64); qy += __shfl_down(qy, o, 64);
        }
        __shared__ float red[4][4];
        const int wv = threadIdx.x >> 6, lane = threadIdx.x & 63;
        if (lane == 0) {
            red[wv][0] = sx; red[wv][1] = sy; red[wv][2] = qx; red[wv][3] = qy;
        }
        __syncthreads();
        if (threadIdx.x == 0) {
            float t0 = red[0][0]+red[1][0]+red[2][0]+red[3][0];
            float t1 = red[0][1]+red[1][1]+red[2][1]+red[3][1];
            float t2 = red[0][2]+red[1][2]+red[2][2]+red[3][2];
            float t3 = red[0][3]+red[1][3]+red[2][3]+red[3][3];
            float* dst = partials + ((size_t)b*576 + blockIdx.x)*4;
            dst[0] = t0; dst[1] = t1; dst[2] = t2; dst[3] = t3;
        }
    }
}

__global__ __launch_bounds__(256)
void stats_finalize(const float* __restrict__ partials, float* __restrict__ ms)
{
    const int b = blockIdx.x;
    const int tid = threadIdx.x;
    float sx=0.f, sy=0.f, qx=0.f, qy=0.f;
    for (int i = tid; i < 576; i += 256) {
        const float* p = partials + ((size_t)b*576 + i)*4;
        sx += p[0]; sy += p[1]; qx += p[2]; qy += p[3];
    }
    __shared__ float r0[256], r1[256], r2[256], r3[256];
    r0[tid]=sx; r1[tid]=sy; r2[tid]=qx; r3[tid]=qy;
    __syncthreads();
    for (int s = 128; s > 0; s >>= 1) {
        if (tid < s) {
            r0[tid]+=r0[tid+s]; r1[tid]+=r1[tid+s];
            r2[tid]+=r2[tid+s]; r3[tid]+=r3[tid+s];
        }
        __syncthreads();
    }
    if (tid == 0) {
        const float N = (float)NPIX;
        float var0 = (r2[0] - r0[0]*r0[0]/N) / (N - 1.f);
        float var1 = (r3[0] - r1[0]*r1[0]/N) / (N - 1.f);
        ms[(b*2+0)*2]   = r0[0]/N;
        ms[(b*2+0)*2+1] = sqrtf(var0);
        ms[(b*2+1)*2]   = r1[0]/N;
        ms[(b*2+1)*2+1] = sqrtf(var1);
    }
}

// ---------------------------------------------------------------------------
// conv v4: wave-synchronous, register-sliding, CHANNEL-PAIRED (2 ch per iter,
// float2 hidden tile). 4 waves x 8 pairs.
// ---------------------------------------------------------------------------
__global__ __launch_bounds__(256)
void conv_fused(const float2* __restrict__ ximg, const void* __restrict__ w1g,
                const void* __restrict__ b1g, const void* __restrict__ w2g,
                const void* __restrict__ b2g, const float* __restrict__ msg,
                float2* __restrict__ rim, const int* DTp)
{
    __shared__ float2 inP[20][21];
    __shared__ float w1s[1152];
    __shared__ float w2s[1152];
    __shared__ float b1s[64];
    __shared__ float2 hidw[4][18*20];
    __shared__ float2 accs[4][256];

    const int dt = *DTp;
    const int b = blockIdx.z, bx = blockIdx.x, by = blockIdx.y;
    const int tid = threadIdx.x;
    const int wv = tid >> 6, lane = tid & 63;

    for (int f = tid; f < 1152; f += 256) {
        w1s[f] = loads1(w1g, dt, f);
        w2s[f] = loads1(w2g, dt, f);
    }
    if (tid < 64) b1s[tid] = loads1(b1g, dt, tid);
    const float mean0 = msg[(b*2+0)*2], istd0 = 1.f/msg[(b*2+0)*2+1];
    const float mean1 = msg[(b*2+1)*2], istd1 = 1.f/msg[(b*2+1)*2+1];
    for (int f = tid; f < 400; f += 256) {
        int yy = f / 20, xx = f - yy*20;
        int gy = by*16 + yy - 2, gx = bx*16 + xx - 2;
        float a = 0.f, c = 0.f;
        if (gy >= 0 && gy < HH && gx >= 0 && gx < WW) {
            float2 v = ximg[(size_t)b*NPIX + gy*WW + gx];
            a = (v.x - mean0)*istd0;
            c = (v.y - mean1)*istd1;
        }
        inP[yy][xx] = make_float2(a, c);
    }
    __syncthreads();

    float a0[4] = {0.f,0.f,0.f,0.f}, a1[4] = {0.f,0.f,0.f,0.f};
    float2* hid = hidw[wv];

    const int c1col = lane % 18;
    const int c1g   = lane / 18;           // 0..3; <3 active
    const int c1y0  = 6 * c1g;
    const int tx = lane & 15, ybase = (lane >> 4) * 4;

    for (int j = 0; j < 8; ++j) {
        const int oa = wv*16 + 2*j;
        const float* wa = &w1s[oa*18];
        const float* wb = &w1s[(oa+1)*18];
        const float boa = b1s[oa], bob = b1s[oa+1];
        if (c1g < 3) {
            float2 r0c0 = inP[c1y0][c1col],   r0c1 = inP[c1y0][c1col+1],   r0c2 = inP[c1y0][c1col+2];
            float2 r1c0 = inP[c1y0+1][c1col], r1c1 = inP[c1y0+1][c1col+1], r1c2 = inP[c1y0+1][c1col+2];
            #pragma unroll
            for (int rr = 0; rr < 6; ++rr) {
                float2 r2c0 = inP[c1y0+rr+2][c1col];
                float2 r2c1 = inP[c1y0+rr+2][c1col+1];
                float2 r2c2 = inP[c1y0+rr+2][c1col+2];
                float accA = boa
                    + wa[0]*r0c0.x + wa[1]*r0c1.x + wa[2]*r0c2.x
                    + wa[3]*r1c0.x + wa[4]*r1c1.x + wa[5]*r1c2.x
                    + wa[6]*r2c0.x + wa[7]*r2c1.x + wa[8]*r2c2.x
                    + wa[9]*r0c0.y  + wa[10]*r0c1.y + wa[11]*r0c2.y
                    + wa[12]*r1c0.y + wa[13]*r1c1.y + wa[14]*r1c2.y
                    + wa[15]*r2c0.y + wa[16]*r2c1.y + wa[17]*r2c2.y;
                float accB = bob
                    + wb[0]*r0c0.x + wb[1]*r0c1.x + wb[2]*r0c2.x
                    + wb[3]*r1c0.x + wb[4]*r1c1.x + wb[5]*r1c2.x
                    + wb[6]*r2c0.x + wb[7]*r2c1.x + wb[8]*r2c2.x
                    + wb[9]*r0c0.y  + wb[10]*r0c1.y + wb[11]*r0c2.y
                    + wb[12]*r1c0.y + wb[13]*r1c1.y + wb[14]*r1c2.y
                    + wb[15]*r2c0.y + wb[16]*r2c1.y + wb[17]*r2c2.y;
                int hy = c1y0 + rr;
                int gy = by*16 + hy - 1, gx = bx*16 + c1col - 1;
                bool inb = (gy >= 0 && gy < HH && gx >= 0 && gx < WW);
                hid[hy*20 + c1col] = inb
                    ? make_float2(fmaxf(accA, 0.f), fmaxf(accB, 0.f))
                    : make_float2(0.f, 0.f);
                r0c0 = r1c0; r0c1 = r1c1; r0c2 = r1c2;
                r1c0 = r2c0; r1c1 = r2c1; r1c2 = r2c2;
            }
        }
        __builtin_amdgcn_wave_barrier();
        {
            const float* pa0 = &w2s[oa*9];        // out0, ch oa
            const float* pa1 = &w2s[(oa+1)*9];    // out0, ch oa+1
            const float* pb0 = &w2s[576 + oa*9];
            const float* pb1 = &w2s[576 + (oa+1)*9];
            float2 h00 = hid[ybase*20 + tx],     h01 = hid[ybase*20 + tx+1],     h02 = hid[ybase*20 + tx+2];
            float2 h10 = hid[(ybase+1)*20 + tx], h11 = hid[(ybase+1)*20 + tx+1], h12 = hid[(ybase+1)*20 + tx+2];
            #pragma unroll
            for (int r = 0; r < 4; ++r) {
                float2 h20 = hid[(ybase+r+2)*20 + tx];
                float2 h21 = hid[(ybase+r+2)*20 + tx+1];
                float2 h22 = hid[(ybase+r+2)*20 + tx+2];
                a0[r] += pa0[0]*h00.x + pa0[1]*h01.x + pa0[2]*h02.x
                       + pa0[3]*h10.x + pa0[4]*h11.x + pa0[5]*h12.x
                       + pa0[6]*h20.x + pa0[7]*h21.x + pa0[8]*h22.x
                       + pa1[0]*h00.y + pa1[1]*h01.y + pa1[2]*h02.y
                       + pa1[3]*h10.y + pa1[4]*h11.y + pa1[5]*h12.y
                       + pa1[6]*h20.y + pa1[7]*h21.y + pa1[8]*h22.y;
                a1[r] += pb0[0]*h00.x + pb0[1]*h01.x + pb0[2]*h02.x
                       + pb0[3]*h10.x + pb0[4]*h11.x + pb0[5]*h12.x
                       + pb0[6]*h20.x + pb0[7]*h21.x + pb0[8]*h22.x
                       + pb1[0]*h00.y + pb1[1]*h01.y + pb1[2]*h02.y
                       + pb1[3]*h10.y + pb1[4]*h11.y + pb1[5]*h12.y
                       + pb1[6]*h20.y + pb1[7]*h21.y + pb1[8]*h22.y;
                h00 = h10; h01 = h11; h02 = h12;
                h10 = h20; h11 = h21; h12 = h22;
            }
        }
        __builtin_amdgcn_wave_barrier();
    }
    #pragma unroll
    for (int r = 0; r < 4; ++r)
        accs[wv][(ybase + r)*16 + tx] = make_float2(a0[r], a1[r]);
    __syncthreads();
    {
        const int p = tid;
        float s0 = loads1(b2g, dt, 0), s1 = loads1(b2g, dt, 1);
        #pragma unroll
        for (int wvi = 0; wvi < 4; ++wvi) {
            s0 += accs[wvi][p].x;
            s1 += accs[wvi][p].y;
        }
        const float std0 = msg[(b*2+0)*2+1], std1 = msg[(b*2+1)*2+1];
        int ty = p >> 4, txx = p & 15;
        rim[(size_t)b*NPIX + (by*16+ty)*WW + (bx*16+txx)]
            = make_float2(s0*std0 + mean0, s1*std1 + mean1);
    }
}

__global__ __launch_bounds__(384)
void predictor(const float2* __restrict__ kimg, const void* __restrict__ wmp,
               const void* __restrict__ bmp, float* __restrict__ prob,
               float* __restrict__ outp, const int* DTp)
{
    const int dt = *DTp;
    const int b = blockIdx.x, w = threadIdx.x;
    float s0 = 0.f, s1 = 0.f;
    for (int h = 0; h < HH; ++h) {
        float2 v = kimg[((size_t)b*HH + h)*WW + w];
        s0 += v.x; s1 += v.y;
    }
    float logit = (s0*loads1(wmp,dt,0) + s1*loads1(wmp,dt,1)) * (1.0f/384.0f)
                + loads1(bmp,dt,0);
    __shared__ float red[8];
    float m = logit;
    for (int o = 32; o > 0; o >>= 1) m = fmaxf(m, __shfl_down(m, o, 64));
    int wid = w >> 6, lane = w & 63;
    if (lane == 0) red[wid] = m;
    __syncthreads();
    if (w == 0) { float mm = red[0]; for (int i = 1; i < 6; ++i) mm = fmaxf(mm, red[i]); red[6] = mm; }
    __syncthreads();
    m = red[6];
    float e = expf(logit - m);
    float s = e;
    for (int o = 32; o > 0; o >>= 1) s += __shfl_down(s, o, 64);
    __syncthreads();
    if (lane == 0) red[wid] = s;
    __syncthreads();
    if (w == 0) { float ss = 0.f; for (int i = 0; i < 6; ++i) ss += red[i]; red[7] = ss; }
    __syncthreads();
    float pr = e / red[7];
    prob[b*WW + w] = pr;
    outp[b*WW + w] = pr;
}

__global__ __launch_bounds__(384)
void update_mask_k(const float* __restrict__ prob, const void* __restrict__ cmask,
                   const void* __restrict__ add_list, const void* __restrict__ itp,
                   float* __restrict__ outm, const int* DTp)
{
    const int dt = *DTp;
    const int b = blockIdx.x, w = threadIdx.x;
    __shared__ float p[384];
    float cm = loads1(cmask, dt, b*WW + w);
    float pv = prob[b*WW + w] * (1.0f - cm);
    p[w] = pv;
    __syncthreads();
    int rank = 0;
    for (int i = 0; i < 384; ++i) {
        float q = p[i];
        rank += (q > pv) || (q == pv && i < w);
    }
    int it = flex_int1(itp);
    if (it < 0 || it > 7) it = 0;
    int addn = flex_int_arr(add_list, b*8 + it);
    float val = cm + ((rank < addn) ? 1.0f : 0.0f);
    outm[b*WW + w] = val;
}

// ---------------------------------------------------------------------------
extern "C" void kernel_launch(void* const* d_in, const int* in_sizes, int n_in,
                              void* d_out, int out_size, void* d_ws, size_t ws_size,
                              hipStream_t stream)
{
    const void* src  = d_in[0];
    const void* tgt  = d_in[1];
    const void* mask = d_in[2];
    const void* sens = d_in[3];
    const void* itp  = d_in[4];
    const void* cmask= d_in[5];
    const void* addl = d_in[7];
    const void* dcw  = d_in[8];
    const void* w1   = d_in[9];
    const void* b1   = d_in[10];
    const void* w2   = d_in[11];
    const void* b2   = d_in[12];
    const void* wmp  = d_in[13];
    const void* bmp  = d_in[14];
    float* out = (float*)d_out;

    float* ws = (float*)d_ws;
    const size_t OFF_XIMG = 9437184;
    const size_t OFF_RIM  = OFF_XIMG + 589824;
    const size_t OFF_MS   = OFF_RIM  + 589824;
    const size_t OFF_PROB = OFF_MS + 8;
    const size_t OFF_FLAG = OFF_PROB + 768;
    const size_t OFF_DT   = OFF_FLAG + 4;
    const size_t OFF_PART = OFF_DT + 4;

    float2* A    = (float2*)ws;
    float2* XIMG = (float2*)(ws + OFF_XIMG);
    float2* RIM  = (float2*)(ws + OFF_RIM);
    float*  MS   = ws + OFF_MS;
    float*  PROB = ws + OFF_PROB;
    int*    FLAG = (int*)(ws + OFF_FLAG);
    int*    DT   = (int*)(ws + OFF_DT);
    float*  PART = ws + OFF_PART;

    const int gRow   = (BB*CC)*48;   // NL=8 row passes
    const int gCol   = (BB*CC)*24;   // NL=16 col passes
    const int gSmallR = BB*48;
    const int gSmallC = BB*24;

    detect_dtype<<<1, 256, 0, stream>>>((const unsigned*)src, DT);
    detect_mask<<<1, 256, 0, stream>>>((const unsigned char*)mask, FLAG);

    fft384<-1,0,0,8><<<gRow, 256, 0, stream>>>(src, A, DT, 1, nullptr, nullptr, nullptr, nullptr, nullptr);
    fft384<-1,1,0,16><<<gCol, 256, 0, stream>>>(A, A, DT, 0, nullptr, nullptr, nullptr, nullptr, nullptr);
    reduce_sens<true><<<dim3((NPIX/256), BB), 256, 0, stream>>>(A, sens, XIMG, DT, PART);
    stats_finalize<<<BB, 256, 0, stream>>>(PART, MS);

    conv_fused<<<dim3(24,24,BB), 256, 0, stream>>>(XIMG, w1, b1, w2, b2, MS, RIM, DT);

    fft384<1,0,1,8><<<gRow, 256, 0, stream>>>(nullptr, A, DT, 0, RIM, sens, nullptr, nullptr, nullptr);
    fft384<1,1,2,16><<<gCol, 256, 0, stream>>>(A, A, DT, 0, tgt, mask, FLAG, dcw, (float2*)out);

    fft384<-1,0,0,8><<<gRow, 256, 0, stream>>>(A, A, DT, 0, nullptr, nullptr, nullptr, nullptr, nullptr);
    fft384<-1,1,0,16><<<gCol, 256, 0, stream>>>(A, A, DT, 0, nullptr, nullptr, nullptr, nullptr, nullptr);
    reduce_sens<false><<<dim3((NPIX/256), BB), 256, 0, stream>>>(A, sens, XIMG, DT, nullptr);

    fft384<1,0,0,8><<<gSmallR, 256, 0, stream>>>(XIMG, XIMG, DT, 0, nullptr, nullptr, nullptr, nullptr, nullptr);
    fft384<1,1,0,16><<<gSmallC, 256, 0, stream>>>(XIMG, XIMG, DT, 0, nullptr, nullptr, nullptr, nullptr, nullptr);

    predictor<<<BB, 384, 0, stream>>>(XIMG, wmp, bmp, PROB, out + 9437184 + 768, DT);
    update_mask_k<<<BB, 384, 0, stream>>>(PROB, cmask, addl, itp, out + 9437184, DT);
}

// Round 24
// 368.835 us; speedup vs baseline: 1.1526x; 1.1526x over previous
//
#include <hip/hip_runtime.h>
#include <hip/hip_bf16.h>
#include <math.h>

#define HH 384
#define WW 384
#define NPIX (HH*WW)        // 147456
#define BB 2
#define CC 16
#define NKF 9437184         // pred_kspace float count

__device__ inline float2 cmul(float2 a, float2 b) {
    return make_float2(a.x*b.x - a.y*b.y, a.x*b.y + a.y*b.x);
}
__device__ inline float bf2f(unsigned short u) {
    union { unsigned int i; float f; } c; c.i = ((unsigned)u) << 16; return c.f;
}
__device__ inline float2 loadc2(const void* p, int dt, size_t i) {
    if (dt == 1) { ushort2 u = ((const ushort2*)p)[i];
        return make_float2(bf2f(u.x), bf2f(u.y)); }
    if (dt == 2) { double2 d = ((const double2*)p)[i];
        return make_float2((float)d.x, (float)d.y); }
    return ((const float2*)p)[i];
}
__device__ inline float loads1(const void* p, int dt, size_t i) {
    if (dt == 1) return bf2f(((const unsigned short*)p)[i]);
    if (dt == 2) return (float)((const double*)p)[i];
    return ((const float*)p)[i];
}
__device__ inline int flex_int1(const void* p) {
    unsigned v = ((const unsigned*)p)[0];
    if (v < 1000000u) return (int)v;
    float f = ((const float*)p)[0];
    if (f > -1e6f && f < 1e6f && f == floorf(f)) return (int)f;
    return (int)((const double*)p)[0];
}
__device__ inline int flex_int_arr(const void* p, int i) {
    const unsigned* u = (const unsigned*)p;
    if (u[1] == 0u && u[3] == 0u) return (int)u[2*i];   // int64
    if (u[0] >= 1u && u[0] < 1000000u) return (int)u[i];// int32
    float f = ((const float*)p)[i];
    if (f > -1e6f && f < 1e6f) return (int)f;
    return (int)((const double*)p)[i];
}

__global__ void detect_dtype(const unsigned* __restrict__ q, int* dt)
{
    __shared__ int bad, sig;
    if (threadIdx.x == 0) { bad = 0; sig = 0; }
    __syncthreads();
    const unsigned short* q16 = (const unsigned short*)q;
    int mybad = 0, mysig = 0;
    for (int i = threadIdx.x; i < 8192; i += 256) {
        unsigned short u = q16[i];
        int e = (u >> 7) & 0xFF;
        if (!(e == 0 || (e >= 100 && e <= 140))) mybad++;
    }
    for (int i = threadIdx.x; i < 2048; i += 256) {
        unsigned hi = q[2*i + 1];
        int e = (hi >> 20) & 0x7FF;
        if (e >= 1003 && e <= 1040) mysig++;
    }
    atomicAdd(&bad, mybad);
    atomicAdd(&sig, mysig);
    __syncthreads();
    if (threadIdx.x == 0)
        *dt = (bad < 400) ? 1 : ((sig > 1950) ? 2 : 0);
}

// ---------------------------------------------------------------------------
// FFT-384 wave-synchronous: each 64-lane group transforms one line IN PLACE
// in stage (no work[] scratch). fftshift folded; ortho 1/sqrt(384).
// MODE: 0 plain, 1 load-fused expand, 2 store-fused dc.
// NL=8 (rows) / NL=16 (cols, 128B segments).
// ---------------------------------------------------------------------------
#define SP 385

template<int DIR, int AXIS, int MODE, int NL>
__global__ __launch_bounds__(256)
void fft384(const void* in, float2* out, const int* DTp, int srcExt,
            const void* aux1, const void* aux2,
            const int* FLAGp, const void* dcwp, float2* outk)
{
    __shared__ float2 tw[384];
    __shared__ float2 stage[NL * SP];
    const int tid = threadIdx.x;
    const int dt = (srcExt || MODE) ? *DTp : 0;
    for (int j = tid; j < 384; j += 256) {
        float s, c;
        sincosf(-6.283185307179586f * (float)j / 384.0f, &s, &c);
        tw[j] = make_float2(c, s);
    }
    const int BPI = 384 / NL;
    const int img = blockIdx.x / BPI;
    const int t0  = (blockIdx.x % BPI) * NL;
    const size_t base = (size_t)img * NPIX;
    float2* dst = out + base;

    if (AXIS == 0) {
        if (MODE == 1) {
            const float2* rim = (const float2*)aux1;
            const size_t rbase = (size_t)(img >> 4) * NPIX;
            for (int f = tid; f < NL*384; f += 256) {
                int l = f / 384, n = f - l*384;
                size_t pix = (size_t)(t0 + l)*384 + n;
                stage[l*SP + n] = cmul(rim[rbase + pix], loadc2(aux2, dt, base + pix));
            }
        } else {
            for (int f = tid; f < NL*384; f += 256) {
                int l = f / 384, n = f - l*384;
                stage[l*SP + n] = loadc2(in, dt, base + (size_t)(t0 + l)*384 + n);
            }
        }
    } else {
        for (int f = tid; f < NL*384; f += 256) {
            int l = f & (NL-1), n = f / NL;
            stage[l*SP + n] = loadc2(in, dt, base + (size_t)n*384 + (t0 + l));
        }
    }
    __syncthreads();

    const int g    = tid >> 6;
    const int lane = tid & 63;
    const float SCALE = 0.05103103630798288f;

    for (int it = 0; it < NL/4; ++it) {
        const int l = it*4 + g;
        float2* w = &stage[l*SP];

        // radix-3 decimation, in place: read 6 -> fence -> permuted write
        float2 v6[6];
        #pragma unroll
        for (int m = 0; m < 6; ++m) v6[m] = w[lane + 64*m];
        __builtin_amdgcn_wave_barrier();
        #pragma unroll
        for (int m = 0; m < 6; ++m) {
            int n = lane + 64*m;
            float sgn = (n & 1) ? -1.f : 1.f;
            int q = n / 3;
            int r3 = n - 3*q;
            w[r3*128 + q] = make_float2(v6[m].x*sgn, v6[m].y*sgn);
        }
        __builtin_amdgcn_wave_barrier();

        // 3 x 128-pt DIF radix-2 (wave-local: pair (i,i+h) owned by one lane)
        #pragma unroll
        for (int s = 0; s < 7; ++s) {
            const int h = 64 >> s;
            const int tstep = 3 << s;
            const int j = lane & (h-1);
            const int i = ((lane & ~(h-1)) << 1) | j;
            float2 t = tw[j * tstep];
            if (DIR < 0) t.y = -t.y;
            #pragma unroll
            for (int n1 = 0; n1 < 3; ++n1) {
                float2* a = w + (n1 << 7);
                float2 u = a[i], vv = a[i+h];
                float2 d = make_float2(u.x - vv.x, u.y - vv.y);
                a[i]   = make_float2(u.x + vv.x, u.y + vv.y);
                a[i+h] = cmul(d, t);
            }
            __builtin_amdgcn_wave_barrier();
        }

        // radix-3 combine, in place: read both halves -> fence -> write
        float2 A0[2], A1[2], A2[2];
        #pragma unroll
        for (int half = 0; half < 2; ++half) {
            int k2 = lane + 64*half;
            int r  = __brev((unsigned)k2) >> 25;
            A0[half] = w[r]; A1[half] = w[128 + r]; A2[half] = w[256 + r];
        }
        __builtin_amdgcn_wave_barrier();
        #pragma unroll
        for (int half = 0; half < 2; ++half) {
            int k2 = lane + 64*half;
            float2 t1 = tw[k2];
            float2 t2 = tw[(2*k2) % 384];
            float2 w3 = tw[128], w3b = tw[256];
            if (DIR < 0) { t1.y=-t1.y; t2.y=-t2.y; w3.y=-w3.y; w3b.y=-w3b.y; }
            float2 b1 = cmul(A1[half], t1), b2 = cmul(A2[half], t2);
            float2 a0 = A0[half];
            float2 X0 = make_float2(a0.x + b1.x + b2.x, a0.y + b1.y + b2.y);
            float2 c1 = cmul(w3, b1), c2 = cmul(w3b, b2);
            float2 X1 = make_float2(a0.x + c1.x + c2.x, a0.y + c1.y + c2.y);
            float2 d1 = cmul(w3b, b1), d2 = cmul(w3, b2);
            float2 X2 = make_float2(a0.x + d1.x + d2.x, a0.y + d1.y + d2.y);
            float sc = (k2 & 1) ? -SCALE : SCALE;
            w[k2      ] = make_float2(X0.x*sc, X0.y*sc);
            w[k2 + 128] = make_float2(X1.x*sc, X1.y*sc);
            w[k2 + 256] = make_float2(X2.x*sc, X2.y*sc);
        }
        __builtin_amdgcn_wave_barrier();
    }
    __syncthreads();

    if (AXIS == 0) {
        for (int f = tid; f < NL*384; f += 256) {
            int l = f / 384, n = f - l*384;
            dst[(size_t)(t0 + l)*384 + n] = stage[l*SP + n];
        }
    } else {
        if (MODE == 2) {
            const int fl = *FLAGp;
            const float dw = loads1(dcwp, dt, 0);
            const int bb = img >> 4;
            for (int f = tid; f < NL*384; f += 256) {
                int l = f & (NL-1), n = f / NL;
                int wcol = t0 + l;
                size_t pix = (size_t)n*384 + wcol;
                float2 v = stage[l*SP + n];
                int m;
                switch (fl) {
                    case 0:  m = ((const unsigned char*)aux2)[bb*384 + wcol] != 0; break;
                    case 4:  m = ((const unsigned short*)aux2)[bb*384 + wcol] != 0; break;
                    case 3:  m = ((const unsigned long long*)aux2)[bb*384 + wcol] != 0ULL; break;
                    default: m = ((const unsigned int*)aux2)[bb*384 + wcol] != 0u; break;
                }
                if (m) {
                    float2 r = loadc2(aux1, dt, base + pix);
                    v.x -= (v.x - r.x)*dw;
                    v.y -= (v.y - r.y)*dw;
                }
                dst[pix] = v;
                outk[base + pix] = v;
            }
        } else {
            for (int f = tid; f < NL*384; f += 256) {
                int l = f & (NL-1), n = f / NL;
                dst[(size_t)n*384 + (t0 + l)] = stage[l*SP + n];
            }
        }
    }
}

__global__ void detect_mask(const unsigned char* __restrict__ m, int* flag)
{
    __shared__ int sA, sB, sC, sD, sE;
    if (threadIdx.x == 0) { sA = sB = sC = sD = sE = 0; }
    __syncthreads();
    for (int i = threadIdx.x; i < 768; i += 256) {
        unsigned char v = m[i];
        if (v > 1) atomicOr(&sA, 1);
        if ((i & 3) && v) atomicOr(&sB, 1);
    }
    const unsigned short* m16 = (const unsigned short*)m;
    for (int i = threadIdx.x; i < 384; i += 256)
        if (!(i & 1) && m16[i]) atomicOr(&sC, 1);
    const unsigned int* m32 = (const unsigned int*)m;
    for (int i = threadIdx.x; i < 192; i += 256) {
        if ((i & 1) && m32[i]) atomicOr(&sD, 1);
        if (!(i & 1) && m32[i]) atomicOr(&sE, 1);
    }
    __syncthreads();
    if (threadIdx.x == 0) {
        int f;
        if (!sA) { if (sB) f = 0; else if (sD) f = 2; else f = 3; }
        else     { if (sC) f = 4; else if (sE) f = 2; else f = 3; }
        *flag = f;
    }
}

template<bool WITH_STATS>
__global__ __launch_bounds__(256)
void reduce_sens(const float2* __restrict__ xin, const void* __restrict__ sens,
                 float2* __restrict__ ximg, const int* DTp,
                 float* __restrict__ partials)
{
    const int dt = *DTp;
    const int b = blockIdx.y;
    const int p = blockIdx.x*256 + threadIdx.x;
    float2 acc = make_float2(0.f, 0.f);
    for (int c = 0; c < CC; ++c) {
        size_t o = ((size_t)(b*CC + c))*NPIX + p;
        float2 a = xin[o];
        float2 s = loadc2(sens, dt, o);
        acc.x += a.x*s.x + a.y*s.y;
        acc.y += a.y*s.x - a.x*s.y;
    }
    ximg[(size_t)b*NPIX + p] = acc;
    if (WITH_STATS) {
        float sx = acc.x, sy = acc.y, qx = acc.x*acc.x, qy = acc.y*acc.y;
        #pragma unroll
        for (int o = 32; o > 0; o >>= 1) {
            sx += __shfl_down(sx, o, 64); sy += __shfl_down(sy, o, 64);
            qx += __shfl_down(qx, o, 64); qy += __shfl_down(qy, o, 64);
        }
        __shared__ float red[4][4];
        const int wv = threadIdx.x >> 6, lane = threadIdx.x & 63;
        if (lane == 0) {
            red[wv][0] = sx; red[wv][1] = sy; red[wv][2] = qx; red[wv][3] = qy;
        }
        __syncthreads();
        if (threadIdx.x == 0) {
            float t0 = red[0][0]+red[1][0]+red[2][0]+red[3][0];
            float t1 = red[0][1]+red[1][1]+red[2][1]+red[3][1];
            float t2 = red[0][2]+red[1][2]+red[2][2]+red[3][2];
            float t3 = red[0][3]+red[1][3]+red[2][3]+red[3][3];
            float* dst = partials + ((size_t)b*576 + blockIdx.x)*4;
            dst[0] = t0; dst[1] = t1; dst[2] = t2; dst[3] = t3;
        }
    }
}

__global__ __launch_bounds__(256)
void stats_finalize(const float* __restrict__ partials, float* __restrict__ ms)
{
    const int b = blockIdx.x;
    const int tid = threadIdx.x;
    float sx=0.f, sy=0.f, qx=0.f, qy=0.f;
    for (int i = tid; i < 576; i += 256) {
        const float* p = partials + ((size_t)b*576 + i)*4;
        sx += p[0]; sy += p[1]; qx += p[2]; qy += p[3];
    }
    __shared__ float r0[256], r1[256], r2[256], r3[256];
    r0[tid]=sx; r1[tid]=sy; r2[tid]=qx; r3[tid]=qy;
    __syncthreads();
    for (int s = 128; s > 0; s >>= 1) {
        if (tid < s) {
            r0[tid]+=r0[tid+s]; r1[tid]+=r1[tid+s];
            r2[tid]+=r2[tid+s]; r3[tid]+=r3[tid+s];
        }
        __syncthreads();
    }
    if (tid == 0) {
        const float N = (float)NPIX;
        float var0 = (r2[0] - r0[0]*r0[0]/N) / (N - 1.f);
        float var1 = (r3[0] - r1[0]*r1[0]/N) / (N - 1.f);
        ms[(b*2+0)*2]   = r0[0]/N;
        ms[(b*2+0)*2+1] = sqrtf(var0);
        ms[(b*2+1)*2]   = r1[0]/N;
        ms[(b*2+1)*2+1] = sqrtf(var1);
    }
}

// conv v4 (round-22, verified): wave-synchronous, sliding, channel-paired
__global__ __launch_bounds__(256)
void conv_fused(const float2* __restrict__ ximg, const void* __restrict__ w1g,
                const void* __restrict__ b1g, const void* __restrict__ w2g,
                const void* __restrict__ b2g, const float* __restrict__ msg,
                float2* __restrict__ rim, const int* DTp)
{
    __shared__ float2 inP[20][21];
    __shared__ float w1s[1152];
    __shared__ float w2s[1152];
    __shared__ float b1s[64];
    __shared__ float2 hidw[4][18*20];
    __shared__ float2 accs[4][256];

    const int dt = *DTp;
    const int b = blockIdx.z, bx = blockIdx.x, by = blockIdx.y;
    const int tid = threadIdx.x;
    const int wv = tid >> 6, lane = tid & 63;

    for (int f = tid; f < 1152; f += 256) {
        w1s[f] = loads1(w1g, dt, f);
        w2s[f] = loads1(w2g, dt, f);
    }
    if (tid < 64) b1s[tid] = loads1(b1g, dt, tid);
    const float mean0 = msg[(b*2+0)*2], istd0 = 1.f/msg[(b*2+0)*2+1];
    const float mean1 = msg[(b*2+1)*2], istd1 = 1.f/msg[(b*2+1)*2+1];
    for (int f = tid; f < 400; f += 256) {
        int yy = f / 20, xx = f - yy*20;
        int gy = by*16 + yy - 2, gx = bx*16 + xx - 2;
        float a = 0.f, c = 0.f;
        if (gy >= 0 && gy < HH && gx >= 0 && gx < WW) {
            float2 v = ximg[(size_t)b*NPIX + gy*WW + gx];
            a = (v.x - mean0)*istd0;
            c = (v.y - mean1)*istd1;
        }
        inP[yy][xx] = make_float2(a, c);
    }
    __syncthreads();

    float a0[4] = {0.f,0.f,0.f,0.f}, a1[4] = {0.f,0.f,0.f,0.f};
    float2* hid = hidw[wv];

    const int c1col = lane % 18;
    const int c1g   = lane / 18;
    const int c1y0  = 6 * c1g;
    const int tx = lane & 15, ybase = (lane >> 4) * 4;

    for (int j = 0; j < 8; ++j) {
        const int oa = wv*16 + 2*j;
        const float* wa = &w1s[oa*18];
        const float* wb = &w1s[(oa+1)*18];
        const float boa = b1s[oa], bob = b1s[oa+1];
        if (c1g < 3) {
            float2 r0c0 = inP[c1y0][c1col],   r0c1 = inP[c1y0][c1col+1],   r0c2 = inP[c1y0][c1col+2];
            float2 r1c0 = inP[c1y0+1][c1col], r1c1 = inP[c1y0+1][c1col+1], r1c2 = inP[c1y0+1][c1col+2];
            #pragma unroll
            for (int rr = 0; rr < 6; ++rr) {
                float2 r2c0 = inP[c1y0+rr+2][c1col];
                float2 r2c1 = inP[c1y0+rr+2][c1col+1];
                float2 r2c2 = inP[c1y0+rr+2][c1col+2];
                float accA = boa
                    + wa[0]*r0c0.x + wa[1]*r0c1.x + wa[2]*r0c2.x
                    + wa[3]*r1c0.x + wa[4]*r1c1.x + wa[5]*r1c2.x
                    + wa[6]*r2c0.x + wa[7]*r2c1.x + wa[8]*r2c2.x
                    + wa[9]*r0c0.y  + wa[10]*r0c1.y + wa[11]*r0c2.y
                    + wa[12]*r1c0.y + wa[13]*r1c1.y + wa[14]*r1c2.y
                    + wa[15]*r2c0.y + wa[16]*r2c1.y + wa[17]*r2c2.y;
                float accB = bob
                    + wb[0]*r0c0.x + wb[1]*r0c1.x + wb[2]*r0c2.x
                    + wb[3]*r1c0.x + wb[4]*r1c1.x + wb[5]*r1c2.x
                    + wb[6]*r2c0.x + wb[7]*r2c1.x + wb[8]*r2c2.x
                    + wb[9]*r0c0.y  + wb[10]*r0c1.y + wb[11]*r0c2.y
                    + wb[12]*r1c0.y + wb[13]*r1c1.y + wb[14]*r1c2.y
                    + wb[15]*r2c0.y + wb[16]*r2c1.y + wb[17]*r2c2.y;
                int hy = c1y0 + rr;
                int gy = by*16 + hy - 1, gx = bx*16 + c1col - 1;
                bool inb = (gy >= 0 && gy < HH && gx >= 0 && gx < WW);
                hid[hy*20 + c1col] = inb
                    ? make_float2(fmaxf(accA, 0.f), fmaxf(accB, 0.f))
                    : make_float2(0.f, 0.f);
                r0c0 = r1c0; r0c1 = r1c1; r0c2 = r1c2;
                r1c0 = r2c0; r1c1 = r2c1; r1c2 = r2c2;
            }
        }
        __builtin_amdgcn_wave_barrier();
        {
            const float* pa0 = &w2s[oa*9];
            const float* pa1 = &w2s[(oa+1)*9];
            const float* pb0 = &w2s[576 + oa*9];
            const float* pb1 = &w2s[576 + (oa+1)*9];
            float2 h00 = hid[ybase*20 + tx],     h01 = hid[ybase*20 + tx+1],     h02 = hid[ybase*20 + tx+2];
            float2 h10 = hid[(ybase+1)*20 + tx], h11 = hid[(ybase+1)*20 + tx+1], h12 = hid[(ybase+1)*20 + tx+2];
            #pragma unroll
            for (int r = 0; r < 4; ++r) {
                float2 h20 = hid[(ybase+r+2)*20 + tx];
                float2 h21 = hid[(ybase+r+2)*20 + tx+1];
                float2 h22 = hid[(ybase+r+2)*20 + tx+2];
                a0[r] += pa0[0]*h00.x + pa0[1]*h01.x + pa0[2]*h02.x
                       + pa0[3]*h10.x + pa0[4]*h11.x + pa0[5]*h12.x
                       + pa0[6]*h20.x + pa0[7]*h21.x + pa0[8]*h22.x
                       + pa1[0]*h00.y + pa1[1]*h01.y + pa1[2]*h02.y
                       + pa1[3]*h10.y + pa1[4]*h11.y + pa1[5]*h12.y
                       + pa1[6]*h20.y + pa1[7]*h21.y + pa1[8]*h22.y;
                a1[r] += pb0[0]*h00.x + pb0[1]*h01.x + pb0[2]*h02.x
                       + pb0[3]*h10.x + pb0[4]*h11.x + pb0[5]*h12.x
                       + pb0[6]*h20.x + pb0[7]*h21.x + pb0[8]*h22.x
                       + pb1[0]*h00.y + pb1[1]*h01.y + pb1[2]*h02.y
                       + pb1[3]*h10.y + pb1[4]*h11.y + pb1[5]*h12.y
                       + pb1[6]*h20.y + pb1[7]*h21.y + pb1[8]*h22.y;
                h00 = h10; h01 = h11; h02 = h12;
                h10 = h20; h11 = h21; h12 = h22;
            }
        }
        __builtin_amdgcn_wave_barrier();
    }
    #pragma unroll
    for (int r = 0; r < 4; ++r)
        accs[wv][(ybase + r)*16 + tx] = make_float2(a0[r], a1[r]);
    __syncthreads();
    {
        const int p = tid;
        float s0 = loads1(b2g, dt, 0), s1 = loads1(b2g, dt, 1);
        #pragma unroll
        for (int wvi = 0; wvi < 4; ++wvi) {
            s0 += accs[wvi][p].x;
            s1 += accs[wvi][p].y;
        }
        const float std0 = msg[(b*2+0)*2+1], std1 = msg[(b*2+1)*2+1];
        int ty = p >> 4, txx = p & 15;
        rim[(size_t)b*NPIX + (by*16+ty)*WW + (bx*16+txx)]
            = make_float2(s0*std0 + mean0, s1*std1 + mean1);
    }
}

__global__ __launch_bounds__(384)
void predictor(const float2* __restrict__ kimg, const void* __restrict__ wmp,
               const void* __restrict__ bmp, float* __restrict__ prob,
               float* __restrict__ outp, const int* DTp)
{
    const int dt = *DTp;
    const int b = blockIdx.x, w = threadIdx.x;
    float s0 = 0.f, s1 = 0.f;
    for (int h = 0; h < HH; ++h) {
        float2 v = kimg[((size_t)b*HH + h)*WW + w];
        s0 += v.x; s1 += v.y;
    }
    float logit = (s0*loads1(wmp,dt,0) + s1*loads1(wmp,dt,1)) * (1.0f/384.0f)
                + loads1(bmp,dt,0);
    __shared__ float red[8];
    float m = logit;
    for (int o = 32; o > 0; o >>= 1) m = fmaxf(m, __shfl_down(m, o, 64));
    int wid = w >> 6, lane = w & 63;
    if (lane == 0) red[wid] = m;
    __syncthreads();
    if (w == 0) { float mm = red[0]; for (int i = 1; i < 6; ++i) mm = fmaxf(mm, red[i]); red[6] = mm; }
    __syncthreads();
    m = red[6];
    float e = expf(logit - m);
    float s = e;
    for (int o = 32; o > 0; o >>= 1) s += __shfl_down(s, o, 64);
    __syncthreads();
    if (lane == 0) red[wid] = s;
    __syncthreads();
    if (w == 0) { float ss = 0.f; for (int i = 0; i < 6; ++i) ss += red[i]; red[7] = ss; }
    __syncthreads();
    float pr = e / red[7];
    prob[b*WW + w] = pr;
    outp[b*WW + w] = pr;
}

__global__ __launch_bounds__(384)
void update_mask_k(const float* __restrict__ prob, const void* __restrict__ cmask,
                   const void* __restrict__ add_list, const void* __restrict__ itp,
                   float* __restrict__ outm, const int* DTp)
{
    const int dt = *DTp;
    const int b = blockIdx.x, w = threadIdx.x;
    __shared__ float p[384];
    float cm = loads1(cmask, dt, b*WW + w);
    float pv = prob[b*WW + w] * (1.0f - cm);
    p[w] = pv;
    __syncthreads();
    int rank = 0;
    for (int i = 0; i < 384; ++i) {
        float q = p[i];
        rank += (q > pv) || (q == pv && i < w);
    }
    int it = flex_int1(itp);
    if (it < 0 || it > 7) it = 0;
    int addn = flex_int_arr(add_list, b*8 + it);
    float val = cm + ((rank < addn) ? 1.0f : 0.0f);
    outm[b*WW + w] = val;
}

// ---------------------------------------------------------------------------
extern "C" void kernel_launch(void* const* d_in, const int* in_sizes, int n_in,
                              void* d_out, int out_size, void* d_ws, size_t ws_size,
                              hipStream_t stream)
{
    const void* src  = d_in[0];
    const void* tgt  = d_in[1];
    const void* mask = d_in[2];
    const void* sens = d_in[3];
    const void* itp  = d_in[4];
    const void* cmask= d_in[5];
    const void* addl = d_in[7];
    const void* dcw  = d_in[8];
    const void* w1   = d_in[9];
    const void* b1   = d_in[10];
    const void* w2   = d_in[11];
    const void* b2   = d_in[12];
    const void* wmp  = d_in[13];
    const void* bmp  = d_in[14];
    float* out = (float*)d_out;

    float* ws = (float*)d_ws;
    const size_t OFF_XIMG = 9437184;
    const size_t OFF_RIM  = OFF_XIMG + 589824;
    const size_t OFF_MS   = OFF_RIM  + 589824;
    const size_t OFF_PROB = OFF_MS + 8;
    const size_t OFF_FLAG = OFF_PROB + 768;
    const size_t OFF_DT   = OFF_FLAG + 4;
    const size_t OFF_PART = OFF_DT + 4;

    float2* A    = (float2*)ws;
    float2* XIMG = (float2*)(ws + OFF_XIMG);
    float2* RIM  = (float2*)(ws + OFF_RIM);
    float*  MS   = ws + OFF_MS;
    float*  PROB = ws + OFF_PROB;
    int*    FLAG = (int*)(ws + OFF_FLAG);
    int*    DT   = (int*)(ws + OFF_DT);
    float*  PART = ws + OFF_PART;

    const int gRow    = (BB*CC)*48;   // NL=8 row passes
    const int gCol    = (BB*CC)*24;   // NL=16 col passes
    const int gSmallR = BB*48;
    const int gSmallC = BB*24;

    detect_dtype<<<1, 256, 0, stream>>>((const unsigned*)src, DT);
    detect_mask<<<1, 256, 0, stream>>>((const unsigned char*)mask, FLAG);

    fft384<-1,0,0,8><<<gRow, 256, 0, stream>>>(src, A, DT, 1, nullptr, nullptr, nullptr, nullptr, nullptr);
    fft384<-1,1,0,16><<<gCol, 256, 0, stream>>>(A, A, DT, 0, nullptr, nullptr, nullptr, nullptr, nullptr);
    reduce_sens<true><<<dim3((NPIX/256), BB), 256, 0, stream>>>(A, sens, XIMG, DT, PART);
    stats_finalize<<<BB, 256, 0, stream>>>(PART, MS);

    conv_fused<<<dim3(24,24,BB), 256, 0, stream>>>(XIMG, w1, b1, w2, b2, MS, RIM, DT);

    fft384<1,0,1,8><<<gRow, 256, 0, stream>>>(nullptr, A, DT, 0, RIM, sens, nullptr, nullptr, nullptr);
    fft384<1,1,2,16><<<gCol, 256, 0, stream>>>(A, A, DT, 0, tgt, mask, FLAG, dcw, (float2*)out);

    fft384<-1,0,0,8><<<gRow, 256, 0, stream>>>(A, A, DT, 0, nullptr, nullptr, nullptr, nullptr, nullptr);
    fft384<-1,1,0,16><<<gCol, 256, 0, stream>>>(A, A, DT, 0, nullptr, nullptr, nullptr, nullptr, nullptr);
    reduce_sens<false><<<dim3((NPIX/256), BB), 256, 0, stream>>>(A, sens, XIMG, DT, nullptr);

    fft384<1,0,0,8><<<gSmallR, 256, 0, stream>>>(XIMG, XIMG, DT, 0, nullptr, nullptr, nullptr, nullptr, nullptr);
    fft384<1,1,0,16><<<gSmallC, 256, 0, stream>>>(XIMG, XIMG, DT, 0, nullptr, nullptr, nullptr, nullptr, nullptr);

    predictor<<<BB, 384, 0, stream>>>(XIMG, wmp, bmp, PROB, out + 9437184 + 768, DT);
    update_mask_k<<<BB, 384, 0, stream>>>(PROB, cmask, addl, itp, out + 9437184, DT);
}

// Round 25
// 329.678 us; speedup vs baseline: 1.2895x; 1.1188x over previous
//
#include <hip/hip_runtime.h>
#include <hip/hip_bf16.h>
#include <math.h>

#define HH 384
#define WW 384
#define NPIX (HH*WW)        // 147456
#define BB 2
#define CC 16
#define NKF 9437184         // pred_kspace float count

__device__ inline float2 cmul(float2 a, float2 b) {
    return make_float2(a.x*b.x - a.y*b.y, a.x*b.y + a.y*b.x);
}
__device__ inline float bf2f(unsigned short u) {
    union { unsigned int i; float f; } c; c.i = ((unsigned)u) << 16; return c.f;
}
__device__ inline float2 loadc2(const void* p, int dt, size_t i) {
    if (dt == 1) { ushort2 u = ((const ushort2*)p)[i];
        return make_float2(bf2f(u.x), bf2f(u.y)); }
    if (dt == 2) { double2 d = ((const double2*)p)[i];
        return make_float2((float)d.x, (float)d.y); }
    return ((const float2*)p)[i];
}
__device__ inline float loads1(const void* p, int dt, size_t i) {
    if (dt == 1) return bf2f(((const unsigned short*)p)[i]);
    if (dt == 2) return (float)((const double*)p)[i];
    return ((const float*)p)[i];
}
__device__ inline int flex_int1(const void* p) {
    unsigned v = ((const unsigned*)p)[0];
    if (v < 1000000u) return (int)v;
    float f = ((const float*)p)[0];
    if (f > -1e6f && f < 1e6f && f == floorf(f)) return (int)f;
    return (int)((const double*)p)[0];
}
__device__ inline int flex_int_arr(const void* p, int i) {
    const unsigned* u = (const unsigned*)p;
    if (u[1] == 0u && u[3] == 0u) return (int)u[2*i];   // int64
    if (u[0] >= 1u && u[0] < 1000000u) return (int)u[i];// int32
    float f = ((const float*)p)[i];
    if (f > -1e6f && f < 1e6f) return (int)f;
    return (int)((const double*)p)[i];
}

__global__ void detect_dtype(const unsigned* __restrict__ q, int* dt)
{
    __shared__ int bad, sig;
    if (threadIdx.x == 0) { bad = 0; sig = 0; }
    __syncthreads();
    const unsigned short* q16 = (const unsigned short*)q;
    int mybad = 0, mysig = 0;
    for (int i = threadIdx.x; i < 8192; i += 256) {
        unsigned short u = q16[i];
        int e = (u >> 7) & 0xFF;
        if (!(e == 0 || (e >= 100 && e <= 140))) mybad++;
    }
    for (int i = threadIdx.x; i < 2048; i += 256) {
        unsigned hi = q[2*i + 1];
        int e = (hi >> 20) & 0x7FF;
        if (e >= 1003 && e <= 1040) mysig++;
    }
    atomicAdd(&bad, mybad);
    atomicAdd(&sig, mysig);
    __syncthreads();
    if (threadIdx.x == 0)
        *dt = (bad < 400) ? 1 : ((sig > 1950) ? 2 : 0);
}

// ---------------------------------------------------------------------------
// FFT-384 wave-synchronous, 512 threads (8 waves), each wave owns one line.
// In-place in stage; fftshift folded; ortho. MODE: 0 plain, 1 load-fused
// expand, 2 store-fused dc (writes ONLY outk). NL=8 rows / NL=16 cols.
// ---------------------------------------------------------------------------
#define SP 385

template<int DIR, int AXIS, int MODE, int NL>
__global__ __launch_bounds__(512)
void fft384(const void* in, float2* out, const int* DTp, int srcExt,
            const void* aux1, const void* aux2,
            const int* FLAGp, const void* dcwp, float2* outk)
{
    __shared__ float2 tw[384];
    __shared__ float2 stage[NL * SP];
    const int tid = threadIdx.x;
    const int dt = (srcExt || MODE) ? *DTp : 0;
    for (int j = tid; j < 384; j += 512) {
        float s, c;
        sincosf(-6.283185307179586f * (float)j / 384.0f, &s, &c);
        tw[j] = make_float2(c, s);
    }
    const int BPI = 384 / NL;
    const int img = blockIdx.x / BPI;
    const int t0  = (blockIdx.x % BPI) * NL;
    const size_t base = (size_t)img * NPIX;
    float2* dst = out + base;

    if (AXIS == 0) {
        if (MODE == 1) {
            const float2* rim = (const float2*)aux1;
            const size_t rbase = (size_t)(img >> 4) * NPIX;
            for (int f = tid; f < NL*384; f += 512) {
                int l = f / 384, n = f - l*384;
                size_t pix = (size_t)(t0 + l)*384 + n;
                stage[l*SP + n] = cmul(rim[rbase + pix], loadc2(aux2, dt, base + pix));
            }
        } else {
            for (int f = tid; f < NL*384; f += 512) {
                int l = f / 384, n = f - l*384;
                stage[l*SP + n] = loadc2(in, dt, base + (size_t)(t0 + l)*384 + n);
            }
        }
    } else {
        for (int f = tid; f < NL*384; f += 512) {
            int l = f & (NL-1), n = f / NL;
            stage[l*SP + n] = loadc2(in, dt, base + (size_t)n*384 + (t0 + l));
        }
    }
    __syncthreads();

    const int g    = tid >> 6;      // 0..7
    const int lane = tid & 63;
    const float SCALE = 0.05103103630798288f;

    #pragma unroll
    for (int it = 0; it < NL/8; ++it) {
        const int l = it*8 + g;
        float2* w = &stage[l*SP];

        // radix-3 decimation, in place
        float2 v6[6];
        #pragma unroll
        for (int m = 0; m < 6; ++m) v6[m] = w[lane + 64*m];
        __builtin_amdgcn_wave_barrier();
        #pragma unroll
        for (int m = 0; m < 6; ++m) {
            int n = lane + 64*m;
            float sgn = (n & 1) ? -1.f : 1.f;
            int q = n / 3;
            int r3 = n - 3*q;
            w[r3*128 + q] = make_float2(v6[m].x*sgn, v6[m].y*sgn);
        }
        __builtin_amdgcn_wave_barrier();

        // 3 x 128-pt DIF radix-2
        #pragma unroll
        for (int s = 0; s < 7; ++s) {
            const int h = 64 >> s;
            const int tstep = 3 << s;
            const int j = lane & (h-1);
            const int i = ((lane & ~(h-1)) << 1) | j;
            float2 t = tw[j * tstep];
            if (DIR < 0) t.y = -t.y;
            #pragma unroll
            for (int n1 = 0; n1 < 3; ++n1) {
                float2* a = w + (n1 << 7);
                float2 u = a[i], vv = a[i+h];
                float2 d = make_float2(u.x - vv.x, u.y - vv.y);
                a[i]   = make_float2(u.x + vv.x, u.y + vv.y);
                a[i+h] = cmul(d, t);
            }
            __builtin_amdgcn_wave_barrier();
        }

        // radix-3 combine, in place
        float2 A0[2], A1[2], A2[2];
        #pragma unroll
        for (int half = 0; half < 2; ++half) {
            int k2 = lane + 64*half;
            int r  = __brev((unsigned)k2) >> 25;
            A0[half] = w[r]; A1[half] = w[128 + r]; A2[half] = w[256 + r];
        }
        __builtin_amdgcn_wave_barrier();
        #pragma unroll
        for (int half = 0; half < 2; ++half) {
            int k2 = lane + 64*half;
            float2 t1 = tw[k2];
            float2 t2 = tw[(2*k2) % 384];
            float2 w3 = tw[128], w3b = tw[256];
            if (DIR < 0) { t1.y=-t1.y; t2.y=-t2.y; w3.y=-w3.y; w3b.y=-w3b.y; }
            float2 b1 = cmul(A1[half], t1), b2 = cmul(A2[half], t2);
            float2 a0 = A0[half];
            float2 X0 = make_float2(a0.x + b1.x + b2.x, a0.y + b1.y + b2.y);
            float2 c1 = cmul(w3, b1), c2 = cmul(w3b, b2);
            float2 X1 = make_float2(a0.x + c1.x + c2.x, a0.y + c1.y + c2.y);
            float2 d1 = cmul(w3b, b1), d2 = cmul(w3, b2);
            float2 X2 = make_float2(a0.x + d1.x + d2.x, a0.y + d1.y + d2.y);
            float sc = (k2 & 1) ? -SCALE : SCALE;
            w[k2      ] = make_float2(X0.x*sc, X0.y*sc);
            w[k2 + 128] = make_float2(X1.x*sc, X1.y*sc);
            w[k2 + 256] = make_float2(X2.x*sc, X2.y*sc);
        }
        __builtin_amdgcn_wave_barrier();
    }
    __syncthreads();

    if (AXIS == 0) {
        for (int f = tid; f < NL*384; f += 512) {
            int l = f / 384, n = f - l*384;
            dst[(size_t)(t0 + l)*384 + n] = stage[l*SP + n];
        }
    } else {
        if (MODE == 2) {
            const int fl = *FLAGp;
            const float dw = loads1(dcwp, dt, 0);
            const int bb = img >> 4;
            for (int f = tid; f < NL*384; f += 512) {
                int l = f & (NL-1), n = f / NL;
                int wcol = t0 + l;
                size_t pix = (size_t)n*384 + wcol;
                float2 v = stage[l*SP + n];
                int m;
                switch (fl) {
                    case 0:  m = ((const unsigned char*)aux2)[bb*384 + wcol] != 0; break;
                    case 4:  m = ((const unsigned short*)aux2)[bb*384 + wcol] != 0; break;
                    case 3:  m = ((const unsigned long long*)aux2)[bb*384 + wcol] != 0ULL; break;
                    default: m = ((const unsigned int*)aux2)[bb*384 + wcol] != 0u; break;
                }
                if (m) {
                    float2 r = loadc2(aux1, dt, base + pix);
                    v.x -= (v.x - r.x)*dw;
                    v.y -= (v.y - r.y)*dw;
                }
                outk[base + pix] = v;          // pred lives ONLY in d_out
            }
        } else {
            for (int f = tid; f < NL*384; f += 512) {
                int l = f & (NL-1), n = f / NL;
                dst[(size_t)n*384 + (t0 + l)] = stage[l*SP + n];
            }
        }
    }
}

__global__ void detect_mask(const unsigned char* __restrict__ m, int* flag)
{
    __shared__ int sA, sB, sC, sD, sE;
    if (threadIdx.x == 0) { sA = sB = sC = sD = sE = 0; }
    __syncthreads();
    for (int i = threadIdx.x; i < 768; i += 256) {
        unsigned char v = m[i];
        if (v > 1) atomicOr(&sA, 1);
        if ((i & 3) && v) atomicOr(&sB, 1);
    }
    const unsigned short* m16 = (const unsigned short*)m;
    for (int i = threadIdx.x; i < 384; i += 256)
        if (!(i & 1) && m16[i]) atomicOr(&sC, 1);
    const unsigned int* m32 = (const unsigned int*)m;
    for (int i = threadIdx.x; i < 192; i += 256) {
        if ((i & 1) && m32[i]) atomicOr(&sD, 1);
        if (!(i & 1) && m32[i]) atomicOr(&sE, 1);
    }
    __syncthreads();
    if (threadIdx.x == 0) {
        int f;
        if (!sA) { if (sB) f = 0; else if (sD) f = 2; else f = 3; }
        else     { if (sC) f = 4; else if (sE) f = 2; else f = 3; }
        *flag = f;
    }
}

template<bool WITH_STATS>
__global__ __launch_bounds__(256)
void reduce_sens(const float2* __restrict__ xin, const void* __restrict__ sens,
                 float2* __restrict__ ximg, const int* DTp,
                 float* __restrict__ partials)
{
    const int dt = *DTp;
    const int b = blockIdx.y;
    const int p = blockIdx.x*256 + threadIdx.x;
    float2 acc = make_float2(0.f, 0.f);
    for (int c = 0; c < CC; ++c) {
        size_t o = ((size_t)(b*CC + c))*NPIX + p;
        float2 a = xin[o];
        float2 s = loadc2(sens, dt, o);
        acc.x += a.x*s.x + a.y*s.y;
        acc.y += a.y*s.x - a.x*s.y;
    }
    ximg[(size_t)b*NPIX + p] = acc;
    if (WITH_STATS) {
        float sx = acc.x, sy = acc.y, qx = acc.x*acc.x, qy = acc.y*acc.y;
        #pragma unroll
        for (int o = 32; o > 0; o >>= 1) {
            sx += __shfl_down(sx, o, 64); sy += __shfl_down(sy, o, 64);
            qx += __shfl_down(qx, o, 64); qy += __shfl_down(qy, o, 64);
        }
        __shared__ float red[4][4];
        const int wv = threadIdx.x >> 6, lane = threadIdx.x & 63;
        if (lane == 0) {
            red[wv][0] = sx; red[wv][1] = sy; red[wv][2] = qx; red[wv][3] = qy;
        }
        __syncthreads();
        if (threadIdx.x == 0) {
            float t0 = red[0][0]+red[1][0]+red[2][0]+red[3][0];
            float t1 = red[0][1]+red[1][1]+red[2][1]+red[3][1];
            float t2 = red[0][2]+red[1][2]+red[2][2]+red[3][2];
            float t3 = red[0][3]+red[1][3]+red[2][3]+red[3][3];
            float* dst = partials + ((size_t)b*576 + blockIdx.x)*4;
            dst[0] = t0; dst[1] = t1; dst[2] = t2; dst[3] = t3;
        }
    }
}

__global__ __launch_bounds__(256)
void stats_finalize(const float* __restrict__ partials, float* __restrict__ ms)
{
    const int b = blockIdx.x;
    const int tid = threadIdx.x;
    float sx=0.f, sy=0.f, qx=0.f, qy=0.f;
    for (int i = tid; i < 576; i += 256) {
        const float* p = partials + ((size_t)b*576 + i)*4;
        sx += p[0]; sy += p[1]; qx += p[2]; qy += p[3];
    }
    __shared__ float r0[256], r1[256], r2[256], r3[256];
    r0[tid]=sx; r1[tid]=sy; r2[tid]=qx; r3[tid]=qy;
    __syncthreads();
    for (int s = 128; s > 0; s >>= 1) {
        if (tid < s) {
            r0[tid]+=r0[tid+s]; r1[tid]+=r1[tid+s];
            r2[tid]+=r2[tid+s]; r3[tid]+=r3[tid+s];
        }
        __syncthreads();
    }
    if (tid == 0) {
        const float N = (float)NPIX;
        float var0 = (r2[0] - r0[0]*r0[0]/N) / (N - 1.f);
        float var1 = (r3[0] - r1[0]*r1[0]/N) / (N - 1.f);
        ms[(b*2+0)*2]   = r0[0]/N;
        ms[(b*2+0)*2+1] = sqrtf(var0);
        ms[(b*2+1)*2]   = r1[0]/N;
        ms[(b*2+1)*2+1] = sqrtf(var1);
    }
}

// conv v4 (verified): wave-synchronous, sliding, channel-paired
__global__ __launch_bounds__(256)
void conv_fused(const float2* __restrict__ ximg, const void* __restrict__ w1g,
                const void* __restrict__ b1g, const void* __restrict__ w2g,
                const void* __restrict__ b2g, const float* __restrict__ msg,
                float2* __restrict__ rim, const int* DTp)
{
    __shared__ float2 inP[20][21];
    __shared__ float w1s[1152];
    __shared__ float w2s[1152];
    __shared__ float b1s[64];
    __shared__ float2 hidw[4][18*20];
    __shared__ float2 accs[4][256];

    const int dt = *DTp;
    const int b = blockIdx.z, bx = blockIdx.x, by = blockIdx.y;
    const int tid = threadIdx.x;
    const int wv = tid >> 6, lane = tid & 63;

    for (int f = tid; f < 1152; f += 256) {
        w1s[f] = loads1(w1g, dt, f);
        w2s[f] = loads1(w2g, dt, f);
    }
    if (tid < 64) b1s[tid] = loads1(b1g, dt, tid);
    const float mean0 = msg[(b*2+0)*2], istd0 = 1.f/msg[(b*2+0)*2+1];
    const float mean1 = msg[(b*2+1)*2], istd1 = 1.f/msg[(b*2+1)*2+1];
    for (int f = tid; f < 400; f += 256) {
        int yy = f / 20, xx = f - yy*20;
        int gy = by*16 + yy - 2, gx = bx*16 + xx - 2;
        float a = 0.f, c = 0.f;
        if (gy >= 0 && gy < HH && gx >= 0 && gx < WW) {
            float2 v = ximg[(size_t)b*NPIX + gy*WW + gx];
            a = (v.x - mean0)*istd0;
            c = (v.y - mean1)*istd1;
        }
        inP[yy][xx] = make_float2(a, c);
    }
    __syncthreads();

    float a0[4] = {0.f,0.f,0.f,0.f}, a1[4] = {0.f,0.f,0.f,0.f};
    float2* hid = hidw[wv];

    const int c1col = lane % 18;
    const int c1g   = lane / 18;
    const int c1y0  = 6 * c1g;
    const int tx = lane & 15, ybase = (lane >> 4) * 4;

    for (int j = 0; j < 8; ++j) {
        const int oa = wv*16 + 2*j;
        const float* wa = &w1s[oa*18];
        const float* wb = &w1s[(oa+1)*18];
        const float boa = b1s[oa], bob = b1s[oa+1];
        if (c1g < 3) {
            float2 r0c0 = inP[c1y0][c1col],   r0c1 = inP[c1y0][c1col+1],   r0c2 = inP[c1y0][c1col+2];
            float2 r1c0 = inP[c1y0+1][c1col], r1c1 = inP[c1y0+1][c1col+1], r1c2 = inP[c1y0+1][c1col+2];
            #pragma unroll
            for (int rr = 0; rr < 6; ++rr) {
                float2 r2c0 = inP[c1y0+rr+2][c1col];
                float2 r2c1 = inP[c1y0+rr+2][c1col+1];
                float2 r2c2 = inP[c1y0+rr+2][c1col+2];
                float accA = boa
                    + wa[0]*r0c0.x + wa[1]*r0c1.x + wa[2]*r0c2.x
                    + wa[3]*r1c0.x + wa[4]*r1c1.x + wa[5]*r1c2.x
                    + wa[6]*r2c0.x + wa[7]*r2c1.x + wa[8]*r2c2.x
                    + wa[9]*r0c0.y  + wa[10]*r0c1.y + wa[11]*r0c2.y
                    + wa[12]*r1c0.y + wa[13]*r1c1.y + wa[14]*r1c2.y
                    + wa[15]*r2c0.y + wa[16]*r2c1.y + wa[17]*r2c2.y;
                float accB = bob
                    + wb[0]*r0c0.x + wb[1]*r0c1.x + wb[2]*r0c2.x
                    + wb[3]*r1c0.x + wb[4]*r1c1.x + wb[5]*r1c2.x
                    + wb[6]*r2c0.x + wb[7]*r2c1.x + wb[8]*r2c2.x
                    + wb[9]*r0c0.y  + wb[10]*r0c1.y + wb[11]*r0c2.y
                    + wb[12]*r1c0.y + wb[13]*r1c1.y + wb[14]*r1c2.y
                    + wb[15]*r2c0.y + wb[16]*r2c1.y + wb[17]*r2c2.y;
                int hy = c1y0 + rr;
                int gy = by*16 + hy - 1, gx = bx*16 + c1col - 1;
                bool inb = (gy >= 0 && gy < HH && gx >= 0 && gx < WW);
                hid[hy*20 + c1col] = inb
                    ? make_float2(fmaxf(accA, 0.f), fmaxf(accB, 0.f))
                    : make_float2(0.f, 0.f);
                r0c0 = r1c0; r0c1 = r1c1; r0c2 = r1c2;
                r1c0 = r2c0; r1c1 = r2c1; r1c2 = r2c2;
            }
        }
        __builtin_amdgcn_wave_barrier();
        {
            const float* pa0 = &w2s[oa*9];
            const float* pa1 = &w2s[(oa+1)*9];
            const float* pb0 = &w2s[576 + oa*9];
            const float* pb1 = &w2s[576 + (oa+1)*9];
            float2 h00 = hid[ybase*20 + tx],     h01 = hid[ybase*20 + tx+1],     h02 = hid[ybase*20 + tx+2];
            float2 h10 = hid[(ybase+1)*20 + tx], h11 = hid[(ybase+1)*20 + tx+1], h12 = hid[(ybase+1)*20 + tx+2];
            #pragma unroll
            for (int r = 0; r < 4; ++r) {
                float2 h20 = hid[(ybase+r+2)*20 + tx];
                float2 h21 = hid[(ybase+r+2)*20 + tx+1];
                float2 h22 = hid[(ybase+r+2)*20 + tx+2];
                a0[r] += pa0[0]*h00.x + pa0[1]*h01.x + pa0[2]*h02.x
                       + pa0[3]*h10.x + pa0[4]*h11.x + pa0[5]*h12.x
                       + pa0[6]*h20.x + pa0[7]*h21.x + pa0[8]*h22.x
                       + pa1[0]*h00.y + pa1[1]*h01.y + pa1[2]*h02.y
                       + pa1[3]*h10.y + pa1[4]*h11.y + pa1[5]*h12.y
                       + pa1[6]*h20.y + pa1[7]*h21.y + pa1[8]*h22.y;
                a1[r] += pb0[0]*h00.x + pb0[1]*h01.x + pb0[2]*h02.x
                       + pb0[3]*h10.x + pb0[4]*h11.x + pb0[5]*h12.x
                       + pb0[6]*h20.x + pb0[7]*h21.x + pb0[8]*h22.x
                       + pb1[0]*h00.y + pb1[1]*h01.y + pb1[2]*h02.y
                       + pb1[3]*h10.y + pb1[4]*h11.y + pb1[5]*h12.y
                       + pb1[6]*h20.y + pb1[7]*h21.y + pb1[8]*h22.y;
                h00 = h10; h01 = h11; h02 = h12;
                h10 = h20; h11 = h21; h12 = h22;
            }
        }
        __builtin_amdgcn_wave_barrier();
    }
    #pragma unroll
    for (int r = 0; r < 4; ++r)
        accs[wv][(ybase + r)*16 + tx] = make_float2(a0[r], a1[r]);
    __syncthreads();
    {
        const int p = tid;
        float s0 = loads1(b2g, dt, 0), s1 = loads1(b2g, dt, 1);
        #pragma unroll
        for (int wvi = 0; wvi < 4; ++wvi) {
            s0 += accs[wvi][p].x;
            s1 += accs[wvi][p].y;
        }
        const float std0 = msg[(b*2+0)*2+1], std1 = msg[(b*2+1)*2+1];
        int ty = p >> 4, txx = p & 15;
        rim[(size_t)b*NPIX + (by*16+ty)*WW + (bx*16+txx)]
            = make_float2(s0*std0 + mean0, s1*std1 + mean1);
    }
}

__global__ __launch_bounds__(384)
void predictor(const float2* __restrict__ kimg, const void* __restrict__ wmp,
               const void* __restrict__ bmp, float* __restrict__ prob,
               float* __restrict__ outp, const int* DTp)
{
    const int dt = *DTp;
    const int b = blockIdx.x, w = threadIdx.x;
    float s0 = 0.f, s1 = 0.f;
    for (int h = 0; h < HH; ++h) {
        float2 v = kimg[((size_t)b*HH + h)*WW + w];
        s0 += v.x; s1 += v.y;
    }
    float logit = (s0*loads1(wmp,dt,0) + s1*loads1(wmp,dt,1)) * (1.0f/384.0f)
                + loads1(bmp,dt,0);
    __shared__ float red[8];
    float m = logit;
    for (int o = 32; o > 0; o >>= 1) m = fmaxf(m, __shfl_down(m, o, 64));
    int wid = w >> 6, lane = w & 63;
    if (lane == 0) red[wid] = m;
    __syncthreads();
    if (w == 0) { float mm = red[0]; for (int i = 1; i < 6; ++i) mm = fmaxf(mm, red[i]); red[6] = mm; }
    __syncthreads();
    m = red[6];
    float e = expf(logit - m);
    float s = e;
    for (int o = 32; o > 0; o >>= 1) s += __shfl_down(s, o, 64);
    __syncthreads();
    if (lane == 0) red[wid] = s;
    __syncthreads();
    if (w == 0) { float ss = 0.f; for (int i = 0; i < 6; ++i) ss += red[i]; red[7] = ss; }
    __syncthreads();
    float pr = e / red[7];
    prob[b*WW + w] = pr;
    outp[b*WW + w] = pr;
}

__global__ __launch_bounds__(384)
void update_mask_k(const float* __restrict__ prob, const void* __restrict__ cmask,
                   const void* __restrict__ add_list, const void* __restrict__ itp,
                   float* __restrict__ outm, const int* DTp)
{
    const int dt = *DTp;
    const int b = blockIdx.x, w = threadIdx.x;
    __shared__ float p[384];
    float cm = loads1(cmask, dt, b*WW + w);
    float pv = prob[b*WW + w] * (1.0f - cm);
    p[w] = pv;
    __syncthreads();
    int rank = 0;
    for (int i = 0; i < 384; ++i) {
        float q = p[i];
        rank += (q > pv) || (q == pv && i < w);
    }
    int it = flex_int1(itp);
    if (it < 0 || it > 7) it = 0;
    int addn = flex_int_arr(add_list, b*8 + it);
    float val = cm + ((rank < addn) ? 1.0f : 0.0f);
    outm[b*WW + w] = val;
}

// ---------------------------------------------------------------------------
extern "C" void kernel_launch(void* const* d_in, const int* in_sizes, int n_in,
                              void* d_out, int out_size, void* d_ws, size_t ws_size,
                              hipStream_t stream)
{
    const void* src  = d_in[0];
    const void* tgt  = d_in[1];
    const void* mask = d_in[2];
    const void* sens = d_in[3];
    const void* itp  = d_in[4];
    const void* cmask= d_in[5];
    const void* addl = d_in[7];
    const void* dcw  = d_in[8];
    const void* w1   = d_in[9];
    const void* b1   = d_in[10];
    const void* w2   = d_in[11];
    const void* b2   = d_in[12];
    const void* wmp  = d_in[13];
    const void* bmp  = d_in[14];
    float* out = (float*)d_out;

    float* ws = (float*)d_ws;
    const size_t OFF_XIMG = 9437184;
    const size_t OFF_RIM  = OFF_XIMG + 589824;
    const size_t OFF_MS   = OFF_RIM  + 589824;
    const size_t OFF_PROB = OFF_MS + 8;
    const size_t OFF_FLAG = OFF_PROB + 768;
    const size_t OFF_DT   = OFF_FLAG + 4;
    const size_t OFF_PART = OFF_DT + 4;

    float2* A    = (float2*)ws;
    float2* XIMG = (float2*)(ws + OFF_XIMG);
    float2* RIM  = (float2*)(ws + OFF_RIM);
    float*  MS   = ws + OFF_MS;
    float*  PROB = ws + OFF_PROB;
    int*    FLAG = (int*)(ws + OFF_FLAG);
    int*    DT   = (int*)(ws + OFF_DT);
    float*  PART = ws + OFF_PART;

    const int gRow    = (BB*CC)*48;   // NL=8 row passes
    const int gCol    = (BB*CC)*24;   // NL=16 col passes
    const int gSmallR = BB*48;
    const int gSmallC = BB*24;

    detect_dtype<<<1, 256, 0, stream>>>((const unsigned*)src, DT);
    detect_mask<<<1, 256, 0, stream>>>((const unsigned char*)mask, FLAG);

    fft384<-1,0,0,8><<<gRow, 512, 0, stream>>>(src, A, DT, 1, nullptr, nullptr, nullptr, nullptr, nullptr);
    fft384<-1,1,0,16><<<gCol, 512, 0, stream>>>(A, A, DT, 0, nullptr, nullptr, nullptr, nullptr, nullptr);
    reduce_sens<true><<<dim3((NPIX/256), BB), 256, 0, stream>>>(A, sens, XIMG, DT, PART);
    stats_finalize<<<BB, 256, 0, stream>>>(PART, MS);

    conv_fused<<<dim3(24,24,BB), 256, 0, stream>>>(XIMG, w1, b1, w2, b2, MS, RIM, DT);

    fft384<1,0,1,8><<<gRow, 512, 0, stream>>>(nullptr, A, DT, 0, RIM, sens, nullptr, nullptr, nullptr);
    // dc fused into col-pass store; pred written ONLY to d_out (f32)
    fft384<1,1,2,16><<<gCol, 512, 0, stream>>>(A, A, DT, 0, tgt, mask, FLAG, dcw, (float2*)out);

    // sens_reduce(pred): row ifft reads pred straight from d_out
    fft384<-1,0,0,8><<<gRow, 512, 0, stream>>>(out, A, DT, 0, nullptr, nullptr, nullptr, nullptr, nullptr);
    fft384<-1,1,0,16><<<gCol, 512, 0, stream>>>(A, A, DT, 0, nullptr, nullptr, nullptr, nullptr, nullptr);
    reduce_sens<false><<<dim3((NPIX/256), BB), 256, 0, stream>>>(A, sens, XIMG, DT, nullptr);

    fft384<1,0,0,8><<<gSmallR, 512, 0, stream>>>(XIMG, XIMG, DT, 0, nullptr, nullptr, nullptr, nullptr, nullptr);
    fft384<1,1,0,16><<<gSmallC, 512, 0, stream>>>(XIMG, XIMG, DT, 0, nullptr, nullptr, nullptr, nullptr, nullptr);

    predictor<<<BB, 384, 0, stream>>>(XIMG, wmp, bmp, PROB, out + 9437184 + 768, DT);
    update_mask_k<<<BB, 384, 0, stream>>>(PROB, cmask, addl, itp, out + 9437184, DT);
}

// Round 26
// 325.812 us; speedup vs baseline: 1.3048x; 1.0119x over previous
//
#include <hip/hip_runtime.h>
#include <hip/hip_bf16.h>
#include <math.h>

#define HH 384
#define WW 384
#define NPIX (HH*WW)        // 147456
#define BB 2
#define CC 16
#define NKF 9437184         // pred_kspace float count

__device__ inline float2 cmul(float2 a, float2 b) {
    return make_float2(a.x*b.x - a.y*b.y, a.x*b.y + a.y*b.x);
}
__device__ inline float bf2f(unsigned short u) {
    union { unsigned int i; float f; } c; c.i = ((unsigned)u) << 16; return c.f;
}
__device__ inline float2 loadc2(const void* p, int dt, size_t i) {
    if (dt == 1) { ushort2 u = ((const ushort2*)p)[i];
        return make_float2(bf2f(u.x), bf2f(u.y)); }
    if (dt == 2) { double2 d = ((const double2*)p)[i];
        return make_float2((float)d.x, (float)d.y); }
    return ((const float2*)p)[i];
}
__device__ inline float loads1(const void* p, int dt, size_t i) {
    if (dt == 1) return bf2f(((const unsigned short*)p)[i]);
    if (dt == 2) return (float)((const double*)p)[i];
    return ((const float*)p)[i];
}
__device__ inline int flex_int1(const void* p) {
    unsigned v = ((const unsigned*)p)[0];
    if (v < 1000000u) return (int)v;
    float f = ((const float*)p)[0];
    if (f > -1e6f && f < 1e6f && f == floorf(f)) return (int)f;
    return (int)((const double*)p)[0];
}
__device__ inline int flex_int_arr(const void* p, int i) {
    const unsigned* u = (const unsigned*)p;
    if (u[1] == 0u && u[3] == 0u) return (int)u[2*i];   // int64
    if (u[0] >= 1u && u[0] < 1000000u) return (int)u[i];// int32
    float f = ((const float*)p)[i];
    if (f > -1e6f && f < 1e6f) return (int)f;
    return (int)((const double*)p)[i];
}

__global__ void detect_dtype(const unsigned* __restrict__ q, int* dt)
{
    __shared__ int bad, sig;
    if (threadIdx.x == 0) { bad = 0; sig = 0; }
    __syncthreads();
    const unsigned short* q16 = (const unsigned short*)q;
    int mybad = 0, mysig = 0;
    for (int i = threadIdx.x; i < 8192; i += 256) {
        unsigned short u = q16[i];
        int e = (u >> 7) & 0xFF;
        if (!(e == 0 || (e >= 100 && e <= 140))) mybad++;
    }
    for (int i = threadIdx.x; i < 2048; i += 256) {
        unsigned hi = q[2*i + 1];
        int e = (hi >> 20) & 0x7FF;
        if (e >= 1003 && e <= 1040) mysig++;
    }
    atomicAdd(&bad, mybad);
    atomicAdd(&sig, mysig);
    __syncthreads();
    if (threadIdx.x == 0)
        *dt = (bad < 400) ? 1 : ((sig > 1950) ? 2 : 0);
}

// ---------------------------------------------------------------------------
// FFT-384 wave-synchronous, 512 threads (8 waves), each wave owns one line.
// MODE: 0 plain, 1 load-fused expand (reads 2 RIM partials + bias + denorm),
// 2 store-fused dc (writes ONLY outk). NL=8 rows / NL=16 cols.
// MODE1 reuses: aux1=RIM(2 halves), aux2=sens, dcwp=b2, outk=(float2*)msg.
// ---------------------------------------------------------------------------
#define SP 385

template<int DIR, int AXIS, int MODE, int NL>
__global__ __launch_bounds__(512)
void fft384(const void* in, float2* out, const int* DTp, int srcExt,
            const void* aux1, const void* aux2,
            const int* FLAGp, const void* dcwp, float2* outk)
{
    __shared__ float2 tw[384];
    __shared__ float2 stage[NL * SP];
    const int tid = threadIdx.x;
    const int dt = (srcExt || MODE) ? *DTp : 0;
    for (int j = tid; j < 384; j += 512) {
        float s, c;
        sincosf(-6.283185307179586f * (float)j / 384.0f, &s, &c);
        tw[j] = make_float2(c, s);
    }
    const int BPI = 384 / NL;
    const int img = blockIdx.x / BPI;
    const int t0  = (blockIdx.x % BPI) * NL;
    const size_t base = (size_t)img * NPIX;
    float2* dst = out + base;

    if (AXIS == 0) {
        if (MODE == 1) {
            const float2* rim = (const float2*)aux1;
            const int bb = img >> 4;
            const size_t rbase = (size_t)bb * NPIX;
            const float* msgf = (const float*)outk;
            const float b20 = loads1(dcwp, dt, 0), b21 = loads1(dcwp, dt, 1);
            const float mean0 = msgf[(bb*2+0)*2], std0 = msgf[(bb*2+0)*2+1];
            const float mean1 = msgf[(bb*2+1)*2], std1 = msgf[(bb*2+1)*2+1];
            for (int f = tid; f < NL*384; f += 512) {
                int l = f / 384, n = f - l*384;
                size_t pix = (size_t)(t0 + l)*384 + n;
                float2 p1 = rim[rbase + pix];
                float2 p2 = rim[(size_t)BB*NPIX + rbase + pix];
                float2 y = make_float2((p1.x + p2.x + b20)*std0 + mean0,
                                       (p1.y + p2.y + b21)*std1 + mean1);
                stage[l*SP + n] = cmul(y, loadc2(aux2, dt, base + pix));
            }
        } else {
            for (int f = tid; f < NL*384; f += 512) {
                int l = f / 384, n = f - l*384;
                stage[l*SP + n] = loadc2(in, dt, base + (size_t)(t0 + l)*384 + n);
            }
        }
    } else {
        for (int f = tid; f < NL*384; f += 512) {
            int l = f & (NL-1), n = f / NL;
            stage[l*SP + n] = loadc2(in, dt, base + (size_t)n*384 + (t0 + l));
        }
    }
    __syncthreads();

    const int g    = tid >> 6;      // 0..7
    const int lane = tid & 63;
    const float SCALE = 0.05103103630798288f;

    #pragma unroll
    for (int it = 0; it < NL/8; ++it) {
        const int l = it*8 + g;
        float2* w = &stage[l*SP];

        float2 v6[6];
        #pragma unroll
        for (int m = 0; m < 6; ++m) v6[m] = w[lane + 64*m];
        __builtin_amdgcn_wave_barrier();
        #pragma unroll
        for (int m = 0; m < 6; ++m) {
            int n = lane + 64*m;
            float sgn = (n & 1) ? -1.f : 1.f;
            int q = n / 3;
            int r3 = n - 3*q;
            w[r3*128 + q] = make_float2(v6[m].x*sgn, v6[m].y*sgn);
        }
        __builtin_amdgcn_wave_barrier();

        #pragma unroll
        for (int s = 0; s < 7; ++s) {
            const int h = 64 >> s;
            const int tstep = 3 << s;
            const int j = lane & (h-1);
            const int i = ((lane & ~(h-1)) << 1) | j;
            float2 t = tw[j * tstep];
            if (DIR < 0) t.y = -t.y;
            #pragma unroll
            for (int n1 = 0; n1 < 3; ++n1) {
                float2* a = w + (n1 << 7);
                float2 u = a[i], vv = a[i+h];
                float2 d = make_float2(u.x - vv.x, u.y - vv.y);
                a[i]   = make_float2(u.x + vv.x, u.y + vv.y);
                a[i+h] = cmul(d, t);
            }
            __builtin_amdgcn_wave_barrier();
        }

        float2 A0[2], A1[2], A2[2];
        #pragma unroll
        for (int half = 0; half < 2; ++half) {
            int k2 = lane + 64*half;
            int r  = __brev((unsigned)k2) >> 25;
            A0[half] = w[r]; A1[half] = w[128 + r]; A2[half] = w[256 + r];
        }
        __builtin_amdgcn_wave_barrier();
        #pragma unroll
        for (int half = 0; half < 2; ++half) {
            int k2 = lane + 64*half;
            float2 t1 = tw[k2];
            float2 t2 = tw[(2*k2) % 384];
            float2 w3 = tw[128], w3b = tw[256];
            if (DIR < 0) { t1.y=-t1.y; t2.y=-t2.y; w3.y=-w3.y; w3b.y=-w3b.y; }
            float2 b1 = cmul(A1[half], t1), b2 = cmul(A2[half], t2);
            float2 a0 = A0[half];
            float2 X0 = make_float2(a0.x + b1.x + b2.x, a0.y + b1.y + b2.y);
            float2 c1 = cmul(w3, b1), c2 = cmul(w3b, b2);
            float2 X1 = make_float2(a0.x + c1.x + c2.x, a0.y + c1.y + c2.y);
            float2 d1 = cmul(w3b, b1), d2 = cmul(w3, b2);
            float2 X2 = make_float2(a0.x + d1.x + d2.x, a0.y + d1.y + d2.y);
            float sc = (k2 & 1) ? -SCALE : SCALE;
            w[k2      ] = make_float2(X0.x*sc, X0.y*sc);
            w[k2 + 128] = make_float2(X1.x*sc, X1.y*sc);
            w[k2 + 256] = make_float2(X2.x*sc, X2.y*sc);
        }
        __builtin_amdgcn_wave_barrier();
    }
    __syncthreads();

    if (AXIS == 0) {
        for (int f = tid; f < NL*384; f += 512) {
            int l = f / 384, n = f - l*384;
            dst[(size_t)(t0 + l)*384 + n] = stage[l*SP + n];
        }
    } else {
        if (MODE == 2) {
            const int fl = *FLAGp;
            const float dw = loads1(dcwp, dt, 0);
            const int bb = img >> 4;
            for (int f = tid; f < NL*384; f += 512) {
                int l = f & (NL-1), n = f / NL;
                int wcol = t0 + l;
                size_t pix = (size_t)n*384 + wcol;
                float2 v = stage[l*SP + n];
                int m;
                switch (fl) {
                    case 0:  m = ((const unsigned char*)aux2)[bb*384 + wcol] != 0; break;
                    case 4:  m = ((const unsigned short*)aux2)[bb*384 + wcol] != 0; break;
                    case 3:  m = ((const unsigned long long*)aux2)[bb*384 + wcol] != 0ULL; break;
                    default: m = ((const unsigned int*)aux2)[bb*384 + wcol] != 0u; break;
                }
                if (m) {
                    float2 r = loadc2(aux1, dt, base + pix);
                    v.x -= (v.x - r.x)*dw;
                    v.y -= (v.y - r.y)*dw;
                }
                outk[base + pix] = v;
            }
        } else {
            for (int f = tid; f < NL*384; f += 512) {
                int l = f & (NL-1), n = f / NL;
                dst[(size_t)n*384 + (t0 + l)] = stage[l*SP + n];
            }
        }
    }
}

__global__ void detect_mask(const unsigned char* __restrict__ m, int* flag)
{
    __shared__ int sA, sB, sC, sD, sE;
    if (threadIdx.x == 0) { sA = sB = sC = sD = sE = 0; }
    __syncthreads();
    for (int i = threadIdx.x; i < 768; i += 256) {
        unsigned char v = m[i];
        if (v > 1) atomicOr(&sA, 1);
        if ((i & 3) && v) atomicOr(&sB, 1);
    }
    const unsigned short* m16 = (const unsigned short*)m;
    for (int i = threadIdx.x; i < 384; i += 256)
        if (!(i & 1) && m16[i]) atomicOr(&sC, 1);
    const unsigned int* m32 = (const unsigned int*)m;
    for (int i = threadIdx.x; i < 192; i += 256) {
        if ((i & 1) && m32[i]) atomicOr(&sD, 1);
        if (!(i & 1) && m32[i]) atomicOr(&sE, 1);
    }
    __syncthreads();
    if (threadIdx.x == 0) {
        int f;
        if (!sA) { if (sB) f = 0; else if (sD) f = 2; else f = 3; }
        else     { if (sC) f = 4; else if (sE) f = 2; else f = 3; }
        *flag = f;
    }
}

template<bool WITH_STATS>
__global__ __launch_bounds__(256)
void reduce_sens(const float2* __restrict__ xin, const void* __restrict__ sens,
                 float2* __restrict__ ximg, const int* DTp,
                 float* __restrict__ partials)
{
    const int dt = *DTp;
    const int b = blockIdx.y;
    const int p = blockIdx.x*256 + threadIdx.x;
    float2 acc = make_float2(0.f, 0.f);
    for (int c = 0; c < CC; ++c) {
        size_t o = ((size_t)(b*CC + c))*NPIX + p;
        float2 a = xin[o];
        float2 s = loadc2(sens, dt, o);
        acc.x += a.x*s.x + a.y*s.y;
        acc.y += a.y*s.x - a.x*s.y;
    }
    ximg[(size_t)b*NPIX + p] = acc;
    if (WITH_STATS) {
        float sx = acc.x, sy = acc.y, qx = acc.x*acc.x, qy = acc.y*acc.y;
        #pragma unroll
        for (int o = 32; o > 0; o >>= 1) {
            sx += __shfl_down(sx, o, 64); sy += __shfl_down(sy, o, 64);
            qx += __shfl_down(qx, o, 64); qy += __shfl_down(qy, o, 64);
        }
        __shared__ float red[4][4];
        const int wv = threadIdx.x >> 6, lane = threadIdx.x & 63;
        if (lane == 0) {
            red[wv][0] = sx; red[wv][1] = sy; red[wv][2] = qx; red[wv][3] = qy;
        }
        __syncthreads();
        if (threadIdx.x == 0) {
            float t0 = red[0][0]+red[1][0]+red[2][0]+red[3][0];
            float t1 = red[0][1]+red[1][1]+red[2][1]+red[3][1];
            float t2 = red[0][2]+red[1][2]+red[2][2]+red[3][2];
            float t3 = red[0][3]+red[1][3]+red[2][3]+red[3][3];
            float* dst = partials + ((size_t)b*576 + blockIdx.x)*4;
            dst[0] = t0; dst[1] = t1; dst[2] = t2; dst[3] = t3;
        }
    }
}

__global__ __launch_bounds__(256)
void stats_finalize(const float* __restrict__ partials, float* __restrict__ ms)
{
    const int b = blockIdx.x;
    const int tid = threadIdx.x;
    float sx=0.f, sy=0.f, qx=0.f, qy=0.f;
    for (int i = tid; i < 576; i += 256) {
        const float* p = partials + ((size_t)b*576 + i)*4;
        sx += p[0]; sy += p[1]; qx += p[2]; qy += p[3];
    }
    __shared__ float r0[256], r1[256], r2[256], r3[256];
    r0[tid]=sx; r1[tid]=sy; r2[tid]=qx; r3[tid]=qy;
    __syncthreads();
    for (int s = 128; s > 0; s >>= 1) {
        if (tid < s) {
            r0[tid]+=r0[tid+s]; r1[tid]+=r1[tid+s];
            r2[tid]+=r2[tid+s]; r3[tid]+=r3[tid+s];
        }
        __syncthreads();
    }
    if (tid == 0) {
        const float N = (float)NPIX;
        float var0 = (r2[0] - r0[0]*r0[0]/N) / (N - 1.f);
        float var1 = (r3[0] - r1[0]*r1[0]/N) / (N - 1.f);
        ms[(b*2+0)*2]   = r0[0]/N;
        ms[(b*2+0)*2+1] = sqrtf(var0);
        ms[(b*2+1)*2]   = r1[0]/N;
        ms[(b*2+1)*2+1] = sqrtf(var1);
    }
}

// ---------------------------------------------------------------------------
// conv v5: channel-split partials. Grid (24,24,BB*2): z = b*2 + half.
// Each block computes RAW partial sum of 32 channels (no bias/denorm) into
// rim[half*BB + b]. Combine fused into MODE1 row-fft.
// ---------------------------------------------------------------------------
__global__ __launch_bounds__(256)
void conv_fused(const float2* __restrict__ ximg, const void* __restrict__ w1g,
                const void* __restrict__ b1g, const void* __restrict__ w2g,
                const void* __restrict__ b2g, const float* __restrict__ msg,
                float2* __restrict__ rim, const int* DTp)
{
    __shared__ float2 inP[20][21];
    __shared__ float w1s[1152];
    __shared__ float w2s[1152];
    __shared__ float b1s[64];
    __shared__ float2 hidw[4][18*20];
    __shared__ float2 accs[4][256];

    const int dt = *DTp;
    const int z = blockIdx.z;
    const int b = z >> 1, half = z & 1;
    const int chbase = half * 32;
    const int bx = blockIdx.x, by = blockIdx.y;
    const int tid = threadIdx.x;
    const int wv = tid >> 6, lane = tid & 63;

    for (int f = tid; f < 1152; f += 256) {
        w1s[f] = loads1(w1g, dt, f);
        w2s[f] = loads1(w2g, dt, f);
    }
    if (tid < 64) b1s[tid] = loads1(b1g, dt, tid);
    const float mean0 = msg[(b*2+0)*2], istd0 = 1.f/msg[(b*2+0)*2+1];
    const float mean1 = msg[(b*2+1)*2], istd1 = 1.f/msg[(b*2+1)*2+1];
    for (int f = tid; f < 400; f += 256) {
        int yy = f / 20, xx = f - yy*20;
        int gy = by*16 + yy - 2, gx = bx*16 + xx - 2;
        float a = 0.f, c = 0.f;
        if (gy >= 0 && gy < HH && gx >= 0 && gx < WW) {
            float2 v = ximg[(size_t)b*NPIX + gy*WW + gx];
            a = (v.x - mean0)*istd0;
            c = (v.y - mean1)*istd1;
        }
        inP[yy][xx] = make_float2(a, c);
    }
    __syncthreads();

    float a0[4] = {0.f,0.f,0.f,0.f}, a1[4] = {0.f,0.f,0.f,0.f};
    float2* hid = hidw[wv];

    const int c1col = lane % 18;
    const int c1g   = lane / 18;
    const int c1y0  = 6 * c1g;
    const int tx = lane & 15, ybase = (lane >> 4) * 4;

    for (int j = 0; j < 4; ++j) {
        const int oa = chbase + wv*8 + 2*j;
        const float* wa = &w1s[oa*18];
        const float* wb = &w1s[(oa+1)*18];
        const float boa = b1s[oa], bob = b1s[oa+1];
        if (c1g < 3) {
            float2 r0c0 = inP[c1y0][c1col],   r0c1 = inP[c1y0][c1col+1],   r0c2 = inP[c1y0][c1col+2];
            float2 r1c0 = inP[c1y0+1][c1col], r1c1 = inP[c1y0+1][c1col+1], r1c2 = inP[c1y0+1][c1col+2];
            #pragma unroll
            for (int rr = 0; rr < 6; ++rr) {
                float2 r2c0 = inP[c1y0+rr+2][c1col];
                float2 r2c1 = inP[c1y0+rr+2][c1col+1];
                float2 r2c2 = inP[c1y0+rr+2][c1col+2];
                float accA = boa
                    + wa[0]*r0c0.x + wa[1]*r0c1.x + wa[2]*r0c2.x
                    + wa[3]*r1c0.x + wa[4]*r1c1.x + wa[5]*r1c2.x
                    + wa[6]*r2c0.x + wa[7]*r2c1.x + wa[8]*r2c2.x
                    + wa[9]*r0c0.y  + wa[10]*r0c1.y + wa[11]*r0c2.y
                    + wa[12]*r1c0.y + wa[13]*r1c1.y + wa[14]*r1c2.y
                    + wa[15]*r2c0.y + wa[16]*r2c1.y + wa[17]*r2c2.y;
                float accB = bob
                    + wb[0]*r0c0.x + wb[1]*r0c1.x + wb[2]*r0c2.x
                    + wb[3]*r1c0.x + wb[4]*r1c1.x + wb[5]*r1c2.x
                    + wb[6]*r2c0.x + wb[7]*r2c1.x + wb[8]*r2c2.x
                    + wb[9]*r0c0.y  + wb[10]*r0c1.y + wb[11]*r0c2.y
                    + wb[12]*r1c0.y + wb[13]*r1c1.y + wb[14]*r1c2.y
                    + wb[15]*r2c0.y + wb[16]*r2c1.y + wb[17]*r2c2.y;
                int hy = c1y0 + rr;
                int gy = by*16 + hy - 1, gx = bx*16 + c1col - 1;
                bool inb = (gy >= 0 && gy < HH && gx >= 0 && gx < WW);
                hid[hy*20 + c1col] = inb
                    ? make_float2(fmaxf(accA, 0.f), fmaxf(accB, 0.f))
                    : make_float2(0.f, 0.f);
                r0c0 = r1c0; r0c1 = r1c1; r0c2 = r1c2;
                r1c0 = r2c0; r1c1 = r2c1; r1c2 = r2c2;
            }
        }
        __builtin_amdgcn_wave_barrier();
        {
            const float* pa0 = &w2s[oa*9];
            const float* pa1 = &w2s[(oa+1)*9];
            const float* pb0 = &w2s[576 + oa*9];
            const float* pb1 = &w2s[576 + (oa+1)*9];
            float2 h00 = hid[ybase*20 + tx],     h01 = hid[ybase*20 + tx+1],     h02 = hid[ybase*20 + tx+2];
            float2 h10 = hid[(ybase+1)*20 + tx], h11 = hid[(ybase+1)*20 + tx+1], h12 = hid[(ybase+1)*20 + tx+2];
            #pragma unroll
            for (int r = 0; r < 4; ++r) {
                float2 h20 = hid[(ybase+r+2)*20 + tx];
                float2 h21 = hid[(ybase+r+2)*20 + tx+1];
                float2 h22 = hid[(ybase+r+2)*20 + tx+2];
                a0[r] += pa0[0]*h00.x + pa0[1]*h01.x + pa0[2]*h02.x
                       + pa0[3]*h10.x + pa0[4]*h11.x + pa0[5]*h12.x
                       + pa0[6]*h20.x + pa0[7]*h21.x + pa0[8]*h22.x
                       + pa1[0]*h00.y + pa1[1]*h01.y + pa1[2]*h02.y
                       + pa1[3]*h10.y + pa1[4]*h11.y + pa1[5]*h12.y
                       + pa1[6]*h20.y + pa1[7]*h21.y + pa1[8]*h22.y;
                a1[r] += pb0[0]*h00.x + pb0[1]*h01.x + pb0[2]*h02.x
                       + pb0[3]*h10.x + pb0[4]*h11.x + pb0[5]*h12.x
                       + pb0[6]*h20.x + pb0[7]*h21.x + pb0[8]*h22.x
                       + pb1[0]*h00.y + pb1[1]*h01.y + pb1[2]*h02.y
                       + pb1[3]*h10.y + pb1[4]*h11.y + pb1[5]*h12.y
                       + pb1[6]*h20.y + pb1[7]*h21.y + pb1[8]*h22.y;
                h00 = h10; h01 = h11; h02 = h12;
                h10 = h20; h11 = h21; h12 = h22;
            }
        }
        __builtin_amdgcn_wave_barrier();
    }
    #pragma unroll
    for (int r = 0; r < 4; ++r)
        accs[wv][(ybase + r)*16 + tx] = make_float2(a0[r], a1[r]);
    __syncthreads();
    {
        const int p = tid;
        float s0 = 0.f, s1 = 0.f;           // RAW partial (no bias/denorm)
        #pragma unroll
        for (int wvi = 0; wvi < 4; ++wvi) {
            s0 += accs[wvi][p].x;
            s1 += accs[wvi][p].y;
        }
        int ty = p >> 4, txx = p & 15;
        rim[((size_t)half*BB + b)*NPIX + (size_t)(by*16+ty)*WW + (bx*16+txx)]
            = make_float2(s0, s1);
    }
}

__global__ __launch_bounds__(384)
void predictor(const float2* __restrict__ kimg, const void* __restrict__ wmp,
               const void* __restrict__ bmp, float* __restrict__ prob,
               float* __restrict__ outp, const int* DTp)
{
    const int dt = *DTp;
    const int b = blockIdx.x, w = threadIdx.x;
    float s0 = 0.f, s1 = 0.f;
    for (int h = 0; h < HH; ++h) {
        float2 v = kimg[((size_t)b*HH + h)*WW + w];
        s0 += v.x; s1 += v.y;
    }
    float logit = (s0*loads1(wmp,dt,0) + s1*loads1(wmp,dt,1)) * (1.0f/384.0f)
                + loads1(bmp,dt,0);
    __shared__ float red[8];
    float m = logit;
    for (int o = 32; o > 0; o >>= 1) m = fmaxf(m, __shfl_down(m, o, 64));
    int wid = w >> 6, lane = w & 63;
    if (lane == 0) red[wid] = m;
    __syncthreads();
    if (w == 0) { float mm = red[0]; for (int i = 1; i < 6; ++i) mm = fmaxf(mm, red[i]); red[6] = mm; }
    __syncthreads();
    m = red[6];
    float e = expf(logit - m);
    float s = e;
    for (int o = 32; o > 0; o >>= 1) s += __shfl_down(s, o, 64);
    __syncthreads();
    if (lane == 0) red[wid] = s;
    __syncthreads();
    if (w == 0) { float ss = 0.f; for (int i = 0; i < 6; ++i) ss += red[i]; red[7] = ss; }
    __syncthreads();
    float pr = e / red[7];
    prob[b*WW + w] = pr;
    outp[b*WW + w] = pr;
}

__global__ __launch_bounds__(384)
void update_mask_k(const float* __restrict__ prob, const void* __restrict__ cmask,
                   const void* __restrict__ add_list, const void* __restrict__ itp,
                   float* __restrict__ outm, const int* DTp)
{
    const int dt = *DTp;
    const int b = blockIdx.x, w = threadIdx.x;
    __shared__ float p[384];
    float cm = loads1(cmask, dt, b*WW + w);
    float pv = prob[b*WW + w] * (1.0f - cm);
    p[w] = pv;
    __syncthreads();
    int rank = 0;
    for (int i = 0; i < 384; ++i) {
        float q = p[i];
        rank += (q > pv) || (q == pv && i < w);
    }
    int it = flex_int1(itp);
    if (it < 0 || it > 7) it = 0;
    int addn = flex_int_arr(add_list, b*8 + it);
    float val = cm + ((rank < addn) ? 1.0f : 0.0f);
    outm[b*WW + w] = val;
}

// ---------------------------------------------------------------------------
extern "C" void kernel_launch(void* const* d_in, const int* in_sizes, int n_in,
                              void* d_out, int out_size, void* d_ws, size_t ws_size,
                              hipStream_t stream)
{
    const void* src  = d_in[0];
    const void* tgt  = d_in[1];
    const void* mask = d_in[2];
    const void* sens = d_in[3];
    const void* itp  = d_in[4];
    const void* cmask= d_in[5];
    const void* addl = d_in[7];
    const void* dcw  = d_in[8];
    const void* w1   = d_in[9];
    const void* b1   = d_in[10];
    const void* w2   = d_in[11];
    const void* b2   = d_in[12];
    const void* wmp  = d_in[13];
    const void* bmp  = d_in[14];
    float* out = (float*)d_out;

    float* ws = (float*)d_ws;
    const size_t OFF_XIMG = 9437184;
    const size_t OFF_RIM  = OFF_XIMG + 589824;
    const size_t OFF_MS   = OFF_RIM  + 2*589824;   // RIM holds 2 halves
    const size_t OFF_PROB = OFF_MS + 8;
    const size_t OFF_FLAG = OFF_PROB + 768;
    const size_t OFF_DT   = OFF_FLAG + 4;
    const size_t OFF_PART = OFF_DT + 4;

    float2* A    = (float2*)ws;
    float2* XIMG = (float2*)(ws + OFF_XIMG);
    float2* RIM  = (float2*)(ws + OFF_RIM);
    float*  MS   = ws + OFF_MS;
    float*  PROB = ws + OFF_PROB;
    int*    FLAG = (int*)(ws + OFF_FLAG);
    int*    DT   = (int*)(ws + OFF_DT);
    float*  PART = ws + OFF_PART;

    const int gRow    = (BB*CC)*48;   // NL=8 row passes
    const int gCol    = (BB*CC)*24;   // NL=16 col passes
    const int gSmallR = BB*48;
    const int gSmallC = BB*24;

    detect_dtype<<<1, 256, 0, stream>>>((const unsigned*)src, DT);
    detect_mask<<<1, 256, 0, stream>>>((const unsigned char*)mask, FLAG);

    fft384<-1,0,0,8><<<gRow, 512, 0, stream>>>(src, A, DT, 1, nullptr, nullptr, nullptr, nullptr, nullptr);
    fft384<-1,1,0,16><<<gCol, 512, 0, stream>>>(A, A, DT, 0, nullptr, nullptr, nullptr, nullptr, nullptr);
    reduce_sens<true><<<dim3((NPIX/256), BB), 256, 0, stream>>>(A, sens, XIMG, DT, PART);
    stats_finalize<<<BB, 256, 0, stream>>>(PART, MS);

    // conv: 2 channel-halves in parallel, raw partials
    conv_fused<<<dim3(24,24,BB*2), 256, 0, stream>>>(XIMG, w1, b1, w2, b2, MS, RIM, DT);

    // MODE1 row-fft: combine partials + bias + denorm + expand (msg via outk, b2 via dcwp)
    fft384<1,0,1,8><<<gRow, 512, 0, stream>>>(nullptr, A, DT, 0, RIM, sens, nullptr, b2, (float2*)MS);
    fft384<1,1,2,16><<<gCol, 512, 0, stream>>>(A, A, DT, 0, tgt, mask, FLAG, dcw, (float2*)out);

    fft384<-1,0,0,8><<<gRow, 512, 0, stream>>>(out, A, DT, 0, nullptr, nullptr, nullptr, nullptr, nullptr);
    fft384<-1,1,0,16><<<gCol, 512, 0, stream>>>(A, A, DT, 0, nullptr, nullptr, nullptr, nullptr, nullptr);
    reduce_sens<false><<<dim3((NPIX/256), BB), 256, 0, stream>>>(A, sens, XIMG, DT, nullptr);

    fft384<1,0,0,8><<<gSmallR, 512, 0, stream>>>(XIMG, XIMG, DT, 0, nullptr, nullptr, nullptr, nullptr, nullptr);
    fft384<1,1,0,16><<<gSmallC, 512, 0, stream>>>(XIMG, XIMG, DT, 0, nullptr, nullptr, nullptr, nullptr, nullptr);

    predictor<<<BB, 384, 0, stream>>>(XIMG, wmp, bmp, PROB, out + 9437184 + 768, DT);
    update_mask_k<<<BB, 384, 0, stream>>>(PROB, cmask, addl, itp, out + 9437184, DT);
}

// Round 27
// 322.210 us; speedup vs baseline: 1.3194x; 1.0112x over previous
//
#include <hip/hip_runtime.h>
#include <hip/hip_bf16.h>
#include <math.h>

#define HH 384
#define WW 384
#define NPIX (HH*WW)        // 147456
#define BB 2
#define CC 16
#define NKF 9437184         // pred_kspace float count

__device__ inline float2 cmul(float2 a, float2 b) {
    return make_float2(a.x*b.x - a.y*b.y, a.x*b.y + a.y*b.x);
}
__device__ inline float bf2f(unsigned short u) {
    union { unsigned int i; float f; } c; c.i = ((unsigned)u) << 16; return c.f;
}
__device__ inline float2 loadc2(const void* p, int dt, size_t i) {
    if (dt == 1) { ushort2 u = ((const ushort2*)p)[i];
        return make_float2(bf2f(u.x), bf2f(u.y)); }
    if (dt == 2) { double2 d = ((const double2*)p)[i];
        return make_float2((float)d.x, (float)d.y); }
    return ((const float2*)p)[i];
}
__device__ inline float loads1(const void* p, int dt, size_t i) {
    if (dt == 1) return bf2f(((const unsigned short*)p)[i]);
    if (dt == 2) return (float)((const double*)p)[i];
    return ((const float*)p)[i];
}
__device__ inline int flex_int1(const void* p) {
    unsigned v = ((const unsigned*)p)[0];
    if (v < 1000000u) return (int)v;
    float f = ((const float*)p)[0];
    if (f > -1e6f && f < 1e6f && f == floorf(f)) return (int)f;
    return (int)((const double*)p)[0];
}
__device__ inline int flex_int_arr(const void* p, int i) {
    const unsigned* u = (const unsigned*)p;
    if (u[1] == 0u && u[3] == 0u) return (int)u[2*i];   // int64
    if (u[0] >= 1u && u[0] < 1000000u) return (int)u[i];// int32
    float f = ((const float*)p)[i];
    if (f > -1e6f && f < 1e6f) return (int)f;
    return (int)((const double*)p)[i];
}

__global__ void detect_dtype(const unsigned* __restrict__ q, int* dt)
{
    __shared__ int bad, sig;
    if (threadIdx.x == 0) { bad = 0; sig = 0; }
    __syncthreads();
    const unsigned short* q16 = (const unsigned short*)q;
    int mybad = 0, mysig = 0;
    for (int i = threadIdx.x; i < 8192; i += 256) {
        unsigned short u = q16[i];
        int e = (u >> 7) & 0xFF;
        if (!(e == 0 || (e >= 100 && e <= 140))) mybad++;
    }
    for (int i = threadIdx.x; i < 2048; i += 256) {
        unsigned hi = q[2*i + 1];
        int e = (hi >> 20) & 0x7FF;
        if (e >= 1003 && e <= 1040) mysig++;
    }
    atomicAdd(&bad, mybad);
    atomicAdd(&sig, mysig);
    __syncthreads();
    if (threadIdx.x == 0)
        *dt = (bad < 400) ? 1 : ((sig > 1950) ? 2 : 0);
}

// ---------------------------------------------------------------------------
// FFT-384 wave-synchronous, 512 threads (8 waves), each wave owns one line.
// MODE: 0 plain, 1 load-fused expand (reads 2 RIM partials + bias + denorm),
// 2 store-fused dc (writes ONLY outk). NL=8 rows / NL=16 cols.
// MODE1 reuses: aux1=RIM(2 halves), aux2=sens, dcwp=b2, outk=(float2*)msg.
// ---------------------------------------------------------------------------
#define SP 385

template<int DIR, int AXIS, int MODE, int NL>
__global__ __launch_bounds__(512)
void fft384(const void* in, float2* out, const int* DTp, int srcExt,
            const void* aux1, const void* aux2,
            const int* FLAGp, const void* dcwp, float2* outk)
{
    __shared__ float2 tw[384];
    __shared__ float2 stage[NL * SP];
    const int tid = threadIdx.x;
    const int dt = (srcExt || MODE) ? *DTp : 0;
    for (int j = tid; j < 384; j += 512) {
        float s, c;
        sincosf(-6.283185307179586f * (float)j / 384.0f, &s, &c);
        tw[j] = make_float2(c, s);
    }
    const int BPI = 384 / NL;
    const int img = blockIdx.x / BPI;
    const int t0  = (blockIdx.x % BPI) * NL;
    const size_t base = (size_t)img * NPIX;
    float2* dst = out + base;

    if (AXIS == 0) {
        if (MODE == 1) {
            const float2* rim = (const float2*)aux1;
            const int bb = img >> 4;
            const size_t rbase = (size_t)bb * NPIX;
            const float* msgf = (const float*)outk;
            const float b20 = loads1(dcwp, dt, 0), b21 = loads1(dcwp, dt, 1);
            const float mean0 = msgf[(bb*2+0)*2], std0 = msgf[(bb*2+0)*2+1];
            const float mean1 = msgf[(bb*2+1)*2], std1 = msgf[(bb*2+1)*2+1];
            for (int f = tid; f < NL*384; f += 512) {
                int l = f / 384, n = f - l*384;
                size_t pix = (size_t)(t0 + l)*384 + n;
                float2 p1 = rim[rbase + pix];
                float2 p2 = rim[(size_t)BB*NPIX + rbase + pix];
                float2 y = make_float2((p1.x + p2.x + b20)*std0 + mean0,
                                       (p1.y + p2.y + b21)*std1 + mean1);
                stage[l*SP + n] = cmul(y, loadc2(aux2, dt, base + pix));
            }
        } else {
            for (int f = tid; f < NL*384; f += 512) {
                int l = f / 384, n = f - l*384;
                stage[l*SP + n] = loadc2(in, dt, base + (size_t)(t0 + l)*384 + n);
            }
        }
    } else {
        for (int f = tid; f < NL*384; f += 512) {
            int l = f & (NL-1), n = f / NL;
            stage[l*SP + n] = loadc2(in, dt, base + (size_t)n*384 + (t0 + l));
        }
    }
    __syncthreads();

    const int g    = tid >> 6;      // 0..7
    const int lane = tid & 63;
    const float SCALE = 0.05103103630798288f;

    #pragma unroll
    for (int it = 0; it < NL/8; ++it) {
        const int l = it*8 + g;
        float2* w = &stage[l*SP];

        float2 v6[6];
        #pragma unroll
        for (int m = 0; m < 6; ++m) v6[m] = w[lane + 64*m];
        __builtin_amdgcn_wave_barrier();
        #pragma unroll
        for (int m = 0; m < 6; ++m) {
            int n = lane + 64*m;
            float sgn = (n & 1) ? -1.f : 1.f;
            int q = n / 3;
            int r3 = n - 3*q;
            w[r3*128 + q] = make_float2(v6[m].x*sgn, v6[m].y*sgn);
        }
        __builtin_amdgcn_wave_barrier();

        #pragma unroll
        for (int s = 0; s < 7; ++s) {
            const int h = 64 >> s;
            const int tstep = 3 << s;
            const int j = lane & (h-1);
            const int i = ((lane & ~(h-1)) << 1) | j;
            float2 t = tw[j * tstep];
            if (DIR < 0) t.y = -t.y;
            #pragma unroll
            for (int n1 = 0; n1 < 3; ++n1) {
                float2* a = w + (n1 << 7);
                float2 u = a[i], vv = a[i+h];
                float2 d = make_float2(u.x - vv.x, u.y - vv.y);
                a[i]   = make_float2(u.x + vv.x, u.y + vv.y);
                a[i+h] = cmul(d, t);
            }
            __builtin_amdgcn_wave_barrier();
        }

        float2 A0[2], A1[2], A2[2];
        #pragma unroll
        for (int half = 0; half < 2; ++half) {
            int k2 = lane + 64*half;
            int r  = __brev((unsigned)k2) >> 25;
            A0[half] = w[r]; A1[half] = w[128 + r]; A2[half] = w[256 + r];
        }
        __builtin_amdgcn_wave_barrier();
        #pragma unroll
        for (int half = 0; half < 2; ++half) {
            int k2 = lane + 64*half;
            float2 t1 = tw[k2];
            float2 t2 = tw[(2*k2) % 384];
            float2 w3 = tw[128], w3b = tw[256];
            if (DIR < 0) { t1.y=-t1.y; t2.y=-t2.y; w3.y=-w3.y; w3b.y=-w3b.y; }
            float2 b1 = cmul(A1[half], t1), b2 = cmul(A2[half], t2);
            float2 a0 = A0[half];
            float2 X0 = make_float2(a0.x + b1.x + b2.x, a0.y + b1.y + b2.y);
            float2 c1 = cmul(w3, b1), c2 = cmul(w3b, b2);
            float2 X1 = make_float2(a0.x + c1.x + c2.x, a0.y + c1.y + c2.y);
            float2 d1 = cmul(w3b, b1), d2 = cmul(w3, b2);
            float2 X2 = make_float2(a0.x + d1.x + d2.x, a0.y + d1.y + d2.y);
            float sc = (k2 & 1) ? -SCALE : SCALE;
            w[k2      ] = make_float2(X0.x*sc, X0.y*sc);
            w[k2 + 128] = make_float2(X1.x*sc, X1.y*sc);
            w[k2 + 256] = make_float2(X2.x*sc, X2.y*sc);
        }
        __builtin_amdgcn_wave_barrier();
    }
    __syncthreads();

    if (AXIS == 0) {
        for (int f = tid; f < NL*384; f += 512) {
            int l = f / 384, n = f - l*384;
            dst[(size_t)(t0 + l)*384 + n] = stage[l*SP + n];
        }
    } else {
        if (MODE == 2) {
            const int fl = *FLAGp;
            const float dw = loads1(dcwp, dt, 0);
            const int bb = img >> 4;
            for (int f = tid; f < NL*384; f += 512) {
                int l = f & (NL-1), n = f / NL;
                int wcol = t0 + l;
                size_t pix = (size_t)n*384 + wcol;
                float2 v = stage[l*SP + n];
                int m;
                switch (fl) {
                    case 0:  m = ((const unsigned char*)aux2)[bb*384 + wcol] != 0; break;
                    case 4:  m = ((const unsigned short*)aux2)[bb*384 + wcol] != 0; break;
                    case 3:  m = ((const unsigned long long*)aux2)[bb*384 + wcol] != 0ULL; break;
                    default: m = ((const unsigned int*)aux2)[bb*384 + wcol] != 0u; break;
                }
                if (m) {
                    float2 r = loadc2(aux1, dt, base + pix);
                    v.x -= (v.x - r.x)*dw;
                    v.y -= (v.y - r.y)*dw;
                }
                outk[base + pix] = v;
            }
        } else {
            for (int f = tid; f < NL*384; f += 512) {
                int l = f & (NL-1), n = f / NL;
                dst[(size_t)n*384 + (t0 + l)] = stage[l*SP + n];
            }
        }
    }
}

__global__ void detect_mask(const unsigned char* __restrict__ m, int* flag)
{
    __shared__ int sA, sB, sC, sD, sE;
    if (threadIdx.x == 0) { sA = sB = sC = sD = sE = 0; }
    __syncthreads();
    for (int i = threadIdx.x; i < 768; i += 256) {
        unsigned char v = m[i];
        if (v > 1) atomicOr(&sA, 1);
        if ((i & 3) && v) atomicOr(&sB, 1);
    }
    const unsigned short* m16 = (const unsigned short*)m;
    for (int i = threadIdx.x; i < 384; i += 256)
        if (!(i & 1) && m16[i]) atomicOr(&sC, 1);
    const unsigned int* m32 = (const unsigned int*)m;
    for (int i = threadIdx.x; i < 192; i += 256) {
        if ((i & 1) && m32[i]) atomicOr(&sD, 1);
        if (!(i & 1) && m32[i]) atomicOr(&sE, 1);
    }
    __syncthreads();
    if (threadIdx.x == 0) {
        int f;
        if (!sA) { if (sB) f = 0; else if (sD) f = 2; else f = 3; }
        else     { if (sC) f = 4; else if (sE) f = 2; else f = 3; }
        *flag = f;
    }
}

template<bool WITH_STATS>
__global__ __launch_bounds__(256)
void reduce_sens(const float2* __restrict__ xin, const void* __restrict__ sens,
                 float2* __restrict__ ximg, const int* DTp,
                 float* __restrict__ partials)
{
    const int dt = *DTp;
    const int b = blockIdx.y;
    const int p = blockIdx.x*256 + threadIdx.x;
    float2 acc = make_float2(0.f, 0.f);
    for (int c = 0; c < CC; ++c) {
        size_t o = ((size_t)(b*CC + c))*NPIX + p;
        float2 a = xin[o];
        float2 s = loadc2(sens, dt, o);
        acc.x += a.x*s.x + a.y*s.y;
        acc.y += a.y*s.x - a.x*s.y;
    }
    ximg[(size_t)b*NPIX + p] = acc;
    if (WITH_STATS) {
        float sx = acc.x, sy = acc.y, qx = acc.x*acc.x, qy = acc.y*acc.y;
        #pragma unroll
        for (int o = 32; o > 0; o >>= 1) {
            sx += __shfl_down(sx, o, 64); sy += __shfl_down(sy, o, 64);
            qx += __shfl_down(qx, o, 64); qy += __shfl_down(qy, o, 64);
        }
        __shared__ float red[4][4];
        const int wv = threadIdx.x >> 6, lane = threadIdx.x & 63;
        if (lane == 0) {
            red[wv][0] = sx; red[wv][1] = sy; red[wv][2] = qx; red[wv][3] = qy;
        }
        __syncthreads();
        if (threadIdx.x == 0) {
            float t0 = red[0][0]+red[1][0]+red[2][0]+red[3][0];
            float t1 = red[0][1]+red[1][1]+red[2][1]+red[3][1];
            float t2 = red[0][2]+red[1][2]+red[2][2]+red[3][2];
            float t3 = red[0][3]+red[1][3]+red[2][3]+red[3][3];
            float* dst = partials + ((size_t)b*576 + blockIdx.x)*4;
            dst[0] = t0; dst[1] = t1; dst[2] = t2; dst[3] = t3;
        }
    }
}

__global__ __launch_bounds__(256)
void stats_finalize(const float* __restrict__ partials, float* __restrict__ ms)
{
    const int b = blockIdx.x;
    const int tid = threadIdx.x;
    float sx=0.f, sy=0.f, qx=0.f, qy=0.f;
    for (int i = tid; i < 576; i += 256) {
        const float* p = partials + ((size_t)b*576 + i)*4;
        sx += p[0]; sy += p[1]; qx += p[2]; qy += p[3];
    }
    __shared__ float r0[256], r1[256], r2[256], r3[256];
    r0[tid]=sx; r1[tid]=sy; r2[tid]=qx; r3[tid]=qy;
    __syncthreads();
    for (int s = 128; s > 0; s >>= 1) {
        if (tid < s) {
            r0[tid]+=r0[tid+s]; r1[tid]+=r1[tid+s];
            r2[tid]+=r2[tid+s]; r3[tid]+=r3[tid+s];
        }
        __syncthreads();
    }
    if (tid == 0) {
        const float N = (float)NPIX;
        float var0 = (r2[0] - r0[0]*r0[0]/N) / (N - 1.f);
        float var1 = (r3[0] - r1[0]*r1[0]/N) / (N - 1.f);
        ms[(b*2+0)*2]   = r0[0]/N;
        ms[(b*2+0)*2+1] = sqrtf(var0);
        ms[(b*2+1)*2]   = r1[0]/N;
        ms[(b*2+1)*2+1] = sqrtf(var1);
    }
}

// ---------------------------------------------------------------------------
// conv v6: channel-split partials, HALF-ONLY weight staging (1152 floats,
// float4 vector loads). Grid (24,24,BB*2): z = b*2 + half. Raw partials to
// rim[half*BB + b]; combine fused into MODE1 row-fft.
// ---------------------------------------------------------------------------
__global__ __launch_bounds__(256)
void conv_fused(const float2* __restrict__ ximg, const void* __restrict__ w1g,
                const void* __restrict__ b1g, const void* __restrict__ w2g,
                const void* __restrict__ b2g, const float* __restrict__ msg,
                float2* __restrict__ rim, const int* DTp)
{
    __shared__ float2 inP[20][21];
    __shared__ float w1s[576];      // 32 ch x 18
    __shared__ float w2s[576];      // [out0: 32x9][out1: 32x9]
    __shared__ float b1s[32];
    __shared__ float2 hidw[4][18*20];
    __shared__ float2 accs[4][256];

    const int dt = *DTp;
    const int z = blockIdx.z;
    const int b = z >> 1, half = z & 1;
    const int chbase = half * 32;
    const int bx = blockIdx.x, by = blockIdx.y;
    const int tid = threadIdx.x;
    const int wv = tid >> 6, lane = tid & 63;

    if (dt == 0) {
        const float4* w1v  = (const float4*)((const float*)w1g + chbase*18);
        const float4* w2v0 = (const float4*)((const float*)w2g + chbase*9);
        const float4* w2v1 = (const float4*)((const float*)w2g + 576 + chbase*9);
        for (int f = tid; f < 144; f += 256) ((float4*)w1s)[f] = w1v[f];
        if (tid < 72)       ((float4*)w2s)[tid]        = w2v0[tid];
        else if (tid < 144) ((float4*)(w2s + 288))[tid - 72] = w2v1[tid - 72];
    } else {
        for (int f = tid; f < 576; f += 256)
            w1s[f] = loads1(w1g, dt, chbase*18 + f);
        for (int f = tid; f < 288; f += 256) {
            w2s[f]       = loads1(w2g, dt, chbase*9 + f);
            w2s[288 + f] = loads1(w2g, dt, 576 + chbase*9 + f);
        }
    }
    if (tid < 32) b1s[tid] = loads1(b1g, dt, chbase + tid);

    const float mean0 = msg[(b*2+0)*2], istd0 = 1.f/msg[(b*2+0)*2+1];
    const float mean1 = msg[(b*2+1)*2], istd1 = 1.f/msg[(b*2+1)*2+1];
    for (int f = tid; f < 400; f += 256) {
        int yy = f / 20, xx = f - yy*20;
        int gy = by*16 + yy - 2, gx = bx*16 + xx - 2;
        float a = 0.f, c = 0.f;
        if (gy >= 0 && gy < HH && gx >= 0 && gx < WW) {
            float2 v = ximg[(size_t)b*NPIX + gy*WW + gx];
            a = (v.x - mean0)*istd0;
            c = (v.y - mean1)*istd1;
        }
        inP[yy][xx] = make_float2(a, c);
    }
    __syncthreads();

    float a0[4] = {0.f,0.f,0.f,0.f}, a1[4] = {0.f,0.f,0.f,0.f};
    float2* hid = hidw[wv];

    const int c1col = lane % 18;
    const int c1g   = lane / 18;
    const int c1y0  = 6 * c1g;
    const int tx = lane & 15, ybase = (lane >> 4) * 4;

    for (int j = 0; j < 4; ++j) {
        const int oc = wv*8 + 2*j;          // half-local channel pair
        const float* wa = &w1s[oc*18];
        const float* wb = &w1s[(oc+1)*18];
        const float boa = b1s[oc], bob = b1s[oc+1];
        if (c1g < 3) {
            float2 r0c0 = inP[c1y0][c1col],   r0c1 = inP[c1y0][c1col+1],   r0c2 = inP[c1y0][c1col+2];
            float2 r1c0 = inP[c1y0+1][c1col], r1c1 = inP[c1y0+1][c1col+1], r1c2 = inP[c1y0+1][c1col+2];
            #pragma unroll
            for (int rr = 0; rr < 6; ++rr) {
                float2 r2c0 = inP[c1y0+rr+2][c1col];
                float2 r2c1 = inP[c1y0+rr+2][c1col+1];
                float2 r2c2 = inP[c1y0+rr+2][c1col+2];
                float accA = boa
                    + wa[0]*r0c0.x + wa[1]*r0c1.x + wa[2]*r0c2.x
                    + wa[3]*r1c0.x + wa[4]*r1c1.x + wa[5]*r1c2.x
                    + wa[6]*r2c0.x + wa[7]*r2c1.x + wa[8]*r2c2.x
                    + wa[9]*r0c0.y  + wa[10]*r0c1.y + wa[11]*r0c2.y
                    + wa[12]*r1c0.y + wa[13]*r1c1.y + wa[14]*r1c2.y
                    + wa[15]*r2c0.y + wa[16]*r2c1.y + wa[17]*r2c2.y;
                float accB = bob
                    + wb[0]*r0c0.x + wb[1]*r0c1.x + wb[2]*r0c2.x
                    + wb[3]*r1c0.x + wb[4]*r1c1.x + wb[5]*r1c2.x
                    + wb[6]*r2c0.x + wb[7]*r2c1.x + wb[8]*r2c2.x
                    + wb[9]*r0c0.y  + wb[10]*r0c1.y + wb[11]*r0c2.y
                    + wb[12]*r1c0.y + wb[13]*r1c1.y + wb[14]*r1c2.y
                    + wb[15]*r2c0.y + wb[16]*r2c1.y + wb[17]*r2c2.y;
                int hy = c1y0 + rr;
                int gy = by*16 + hy - 1, gx = bx*16 + c1col - 1;
                bool inb = (gy >= 0 && gy < HH && gx >= 0 && gx < WW);
                hid[hy*20 + c1col] = inb
                    ? make_float2(fmaxf(accA, 0.f), fmaxf(accB, 0.f))
                    : make_float2(0.f, 0.f);
                r0c0 = r1c0; r0c1 = r1c1; r0c2 = r1c2;
                r1c0 = r2c0; r1c1 = r2c1; r1c2 = r2c2;
            }
        }
        __builtin_amdgcn_wave_barrier();
        {
            const float* pa0 = &w2s[oc*9];          // out0, ch oc
            const float* pa1 = &w2s[(oc+1)*9];      // out0, ch oc+1
            const float* pb0 = &w2s[288 + oc*9];    // out1, ch oc
            const float* pb1 = &w2s[288 + (oc+1)*9];
            float2 h00 = hid[ybase*20 + tx],     h01 = hid[ybase*20 + tx+1],     h02 = hid[ybase*20 + tx+2];
            float2 h10 = hid[(ybase+1)*20 + tx], h11 = hid[(ybase+1)*20 + tx+1], h12 = hid[(ybase+1)*20 + tx+2];
            #pragma unroll
            for (int r = 0; r < 4; ++r) {
                float2 h20 = hid[(ybase+r+2)*20 + tx];
                float2 h21 = hid[(ybase+r+2)*20 + tx+1];
                float2 h22 = hid[(ybase+r+2)*20 + tx+2];
                a0[r] += pa0[0]*h00.x + pa0[1]*h01.x + pa0[2]*h02.x
                       + pa0[3]*h10.x + pa0[4]*h11.x + pa0[5]*h12.x
                       + pa0[6]*h20.x + pa0[7]*h21.x + pa0[8]*h22.x
                       + pa1[0]*h00.y + pa1[1]*h01.y + pa1[2]*h02.y
                       + pa1[3]*h10.y + pa1[4]*h11.y + pa1[5]*h12.y
                       + pa1[6]*h20.y + pa1[7]*h21.y + pa1[8]*h22.y;
                a1[r] += pb0[0]*h00.x + pb0[1]*h01.x + pb0[2]*h02.x
                       + pb0[3]*h10.x + pb0[4]*h11.x + pb0[5]*h12.x
                       + pb0[6]*h20.x + pb0[7]*h21.x + pb0[8]*h22.x
                       + pb1[0]*h00.y + pb1[1]*h01.y + pb1[2]*h02.y
                       + pb1[3]*h10.y + pb1[4]*h11.y + pb1[5]*h12.y
                       + pb1[6]*h20.y + pb1[7]*h21.y + pb1[8]*h22.y;
                h00 = h10; h01 = h11; h02 = h12;
                h10 = h20; h11 = h21; h12 = h22;
            }
        }
        __builtin_amdgcn_wave_barrier();
    }
    #pragma unroll
    for (int r = 0; r < 4; ++r)
        accs[wv][(ybase + r)*16 + tx] = make_float2(a0[r], a1[r]);
    __syncthreads();
    {
        const int p = tid;
        float s0 = 0.f, s1 = 0.f;           // RAW partial
        #pragma unroll
        for (int wvi = 0; wvi < 4; ++wvi) {
            s0 += accs[wvi][p].x;
            s1 += accs[wvi][p].y;
        }
        int ty = p >> 4, txx = p & 15;
        rim[((size_t)half*BB + b)*NPIX + (size_t)(by*16+ty)*WW + (bx*16+txx)]
            = make_float2(s0, s1);
    }
}

__global__ __launch_bounds__(384)
void predictor(const float2* __restrict__ kimg, const void* __restrict__ wmp,
               const void* __restrict__ bmp, float* __restrict__ prob,
               float* __restrict__ outp, const int* DTp)
{
    const int dt = *DTp;
    const int b = blockIdx.x, w = threadIdx.x;
    float s0 = 0.f, s1 = 0.f;
    for (int h = 0; h < HH; ++h) {
        float2 v = kimg[((size_t)b*HH + h)*WW + w];
        s0 += v.x; s1 += v.y;
    }
    float logit = (s0*loads1(wmp,dt,0) + s1*loads1(wmp,dt,1)) * (1.0f/384.0f)
                + loads1(bmp,dt,0);
    __shared__ float red[8];
    float m = logit;
    for (int o = 32; o > 0; o >>= 1) m = fmaxf(m, __shfl_down(m, o, 64));
    int wid = w >> 6, lane = w & 63;
    if (lane == 0) red[wid] = m;
    __syncthreads();
    if (w == 0) { float mm = red[0]; for (int i = 1; i < 6; ++i) mm = fmaxf(mm, red[i]); red[6] = mm; }
    __syncthreads();
    m = red[6];
    float e = expf(logit - m);
    float s = e;
    for (int o = 32; o > 0; o >>= 1) s += __shfl_down(s, o, 64);
    __syncthreads();
    if (lane == 0) red[wid] = s;
    __syncthreads();
    if (w == 0) { float ss = 0.f; for (int i = 0; i < 6; ++i) ss += red[i]; red[7] = ss; }
    __syncthreads();
    float pr = e / red[7];
    prob[b*WW + w] = pr;
    outp[b*WW + w] = pr;
}

__global__ __launch_bounds__(384)
void update_mask_k(const float* __restrict__ prob, const void* __restrict__ cmask,
                   const void* __restrict__ add_list, const void* __restrict__ itp,
                   float* __restrict__ outm, const int* DTp)
{
    const int dt = *DTp;
    const int b = blockIdx.x, w = threadIdx.x;
    __shared__ float p[384];
    float cm = loads1(cmask, dt, b*WW + w);
    float pv = prob[b*WW + w] * (1.0f - cm);
    p[w] = pv;
    __syncthreads();
    int rank = 0;
    for (int i = 0; i < 384; ++i) {
        float q = p[i];
        rank += (q > pv) || (q == pv && i < w);
    }
    int it = flex_int1(itp);
    if (it < 0 || it > 7) it = 0;
    int addn = flex_int_arr(add_list, b*8 + it);
    float val = cm + ((rank < addn) ? 1.0f : 0.0f);
    outm[b*WW + w] = val;
}

// ---------------------------------------------------------------------------
extern "C" void kernel_launch(void* const* d_in, const int* in_sizes, int n_in,
                              void* d_out, int out_size, void* d_ws, size_t ws_size,
                              hipStream_t stream)
{
    const void* src  = d_in[0];
    const void* tgt  = d_in[1];
    const void* mask = d_in[2];
    const void* sens = d_in[3];
    const void* itp  = d_in[4];
    const void* cmask= d_in[5];
    const void* addl = d_in[7];
    const void* dcw  = d_in[8];
    const void* w1   = d_in[9];
    const void* b1   = d_in[10];
    const void* w2   = d_in[11];
    const void* b2   = d_in[12];
    const void* wmp  = d_in[13];
    const void* bmp  = d_in[14];
    float* out = (float*)d_out;

    float* ws = (float*)d_ws;
    const size_t OFF_XIMG = 9437184;
    const size_t OFF_RIM  = OFF_XIMG + 589824;
    const size_t OFF_MS   = OFF_RIM  + 2*589824;   // RIM holds 2 halves
    const size_t OFF_PROB = OFF_MS + 8;
    const size_t OFF_FLAG = OFF_PROB + 768;
    const size_t OFF_DT   = OFF_FLAG + 4;
    const size_t OFF_PART = OFF_DT + 4;

    float2* A    = (float2*)ws;
    float2* XIMG = (float2*)(ws + OFF_XIMG);
    float2* RIM  = (float2*)(ws + OFF_RIM);
    float*  MS   = ws + OFF_MS;
    float*  PROB = ws + OFF_PROB;
    int*    FLAG = (int*)(ws + OFF_FLAG);
    int*    DT   = (int*)(ws + OFF_DT);
    float*  PART = ws + OFF_PART;

    const int gRow    = (BB*CC)*48;   // NL=8 row passes
    const int gCol    = (BB*CC)*24;   // NL=16 col passes
    const int gSmallR = BB*48;
    const int gSmallC = BB*24;

    detect_dtype<<<1, 256, 0, stream>>>((const unsigned*)src, DT);
    detect_mask<<<1, 256, 0, stream>>>((const unsigned char*)mask, FLAG);

    fft384<-1,0,0,8><<<gRow, 512, 0, stream>>>(src, A, DT, 1, nullptr, nullptr, nullptr, nullptr, nullptr);
    fft384<-1,1,0,16><<<gCol, 512, 0, stream>>>(A, A, DT, 0, nullptr, nullptr, nullptr, nullptr, nullptr);
    reduce_sens<true><<<dim3((NPIX/256), BB), 256, 0, stream>>>(A, sens, XIMG, DT, PART);
    stats_finalize<<<BB, 256, 0, stream>>>(PART, MS);

    conv_fused<<<dim3(24,24,BB*2), 256, 0, stream>>>(XIMG, w1, b1, w2, b2, MS, RIM, DT);

    fft384<1,0,1,8><<<gRow, 512, 0, stream>>>(nullptr, A, DT, 0, RIM, sens, nullptr, b2, (float2*)MS);
    fft384<1,1,2,16><<<gCol, 512, 0, stream>>>(A, A, DT, 0, tgt, mask, FLAG, dcw, (float2*)out);

    fft384<-1,0,0,8><<<gRow, 512, 0, stream>>>(out, A, DT, 0, nullptr, nullptr, nullptr, nullptr, nullptr);
    fft384<-1,1,0,16><<<gCol, 512, 0, stream>>>(A, A, DT, 0, nullptr, nullptr, nullptr, nullptr, nullptr);
    reduce_sens<false><<<dim3((NPIX/256), BB), 256, 0, stream>>>(A, sens, XIMG, DT, nullptr);

    fft384<1,0,0,8><<<gSmallR, 512, 0, stream>>>(XIMG, XIMG, DT, 0, nullptr, nullptr, nullptr, nullptr, nullptr);
    fft384<1,1,0,16><<<gSmallC, 512, 0, stream>>>(XIMG, XIMG, DT, 0, nullptr, nullptr, nullptr, nullptr, nullptr);

    predictor<<<BB, 384, 0, stream>>>(XIMG, wmp, bmp, PROB, out + 9437184 + 768, DT);
    update_mask_k<<<BB, 384, 0, stream>>>(PROB, cmask, addl, itp, out + 9437184, DT);
}